// Round 8
// baseline (1172.624 us; speedup 1.0000x reference)
//
#include <hip/hip_runtime.h>
#include <hip/hip_bf16.h>
#include <math.h>

// Problem dims (fixed by reference)
#define C_DIM 256      // h width
#define HID 128
#define HEADS 4
#define OC 64          // per-head out channels
#define FF_DIM 512
#define NLAYERS 12

constexpr float LN_EPS = 1e-5f;
constexpr float SLOPE  = 0.2f;

typedef __attribute__((ext_vector_type(4))) float f32x4;
typedef __attribute__((ext_vector_type(8))) short bf16x8_t;
typedef __attribute__((ext_vector_type(4))) int i32x4;

__device__ __forceinline__ float leaky(float x) { return x > 0.f ? x : SLOPE * x; }

__device__ __forceinline__ float bf2f(unsigned short u) {
    union { unsigned i; float f; } v; v.i = ((unsigned)u) << 16; return v.f;
}
__device__ __forceinline__ void bf2x(unsigned u, float& lo, float& hi) {
    union { unsigned i; float f; } a, b;
    a.i = u << 16; b.i = u & 0xffff0000u;
    lo = a.f; hi = b.f;
}
__device__ __forceinline__ unsigned packbf(float lo, float hi) {
    unsigned a = __bfloat16_as_ushort(__float2bfloat16(lo));
    unsigned b = __bfloat16_as_ushort(__float2bfloat16(hi));
    return a | (b << 16);
}

// ---------------------------------------------------------------------------
// Small utility kernels
// ---------------------------------------------------------------------------
__global__ void zero_i32_kernel(int* __restrict__ p, int n) {
    int i = blockIdx.x * blockDim.x + threadIdx.x;
    if (i < n) p[i] = 0;
}

// bf16-only residual stream: concat writes hb only
__global__ void concat_kernel(const float* __restrict__ hf, const float* __restrict__ hs,
                              __hip_bfloat16* __restrict__ hb, int Nn) {
    int idx = blockIdx.x * blockDim.x + threadIdx.x;
    int total = Nn * C_DIM;
    if (idx < total) {
        int n = idx >> 8;
        int c = idx & 255;
        float v = (c < HID) ? hf[n * HID + c] : hs[n * HID + (c - HID)];
        hb[idx] = __float2bfloat16(v);
    }
}

// Transpose + convert weights: in [L][K][N] fp32 -> out [L][N][K] bf16
__global__ void transp_bf16_kernel(const float* __restrict__ in,
                                   __hip_bfloat16* __restrict__ out, int K, int N) {
    __shared__ float t[32][33];
    const float* inl = in + (size_t)blockIdx.z * K * N;
    __hip_bfloat16* outl = out + (size_t)blockIdx.z * K * N;
    int kb = blockIdx.y * 32, nb = blockIdx.x * 32;
    int tx = threadIdx.x & 31, ty = threadIdx.x >> 5; // 32x8
    #pragma unroll
    for (int r = 0; r < 32; r += 8)
        t[ty + r][tx] = inl[(size_t)(kb + ty + r) * N + nb + tx];
    __syncthreads();
    #pragma unroll
    for (int r = 0; r < 32; r += 8)
        outl[(size_t)(nb + ty + r) * K + kb + tx] = __float2bfloat16(t[tx][ty + r]);
}

// ---------------------------------------------------------------------------
// CSR build: histogram of dst, exclusive scan (wave-shuffle), fill src lists
// ---------------------------------------------------------------------------
__global__ void hist_kernel(const int* __restrict__ dst, int* __restrict__ counts, int E) {
    int e = blockIdx.x * blockDim.x + threadIdx.x;
    if (e < E) atomicAdd(&counts[dst[e]], 1);
}

// single block, 1024 threads = 16 waves. Wave shuffle scan + serial wave-sum scan.
__global__ void scan_kernel(const int* __restrict__ counts, int* __restrict__ offsets,
                            int* __restrict__ cursor, int n) {
    __shared__ int wsum[16];
    __shared__ int carry_s;
    const int lane = threadIdx.x & 63, wid = threadIdx.x >> 6;
    if (threadIdx.x == 0) carry_s = 0;
    __syncthreads();
    for (int base = 0; base < n; base += 1024) {
        int i = base + (int)threadIdx.x;
        int v = (i < n) ? counts[i] : 0;
        int x = v;
        #pragma unroll
        for (int off = 1; off < 64; off <<= 1) {
            int t = __shfl_up(x, off);
            if (lane >= off) x += t;
        }
        if (lane == 63) wsum[wid] = x;
        __syncthreads();
        if (threadIdx.x == 0) {
            int acc = carry_s;
            #pragma unroll
            for (int w = 0; w < 16; ++w) { int t = wsum[w]; wsum[w] = acc; acc += t; }
            carry_s = acc;
        }
        __syncthreads();
        int excl = wsum[wid] + x - v;
        if (i < n) { offsets[i] = excl; cursor[i] = excl; }
        __syncthreads();
    }
    if (threadIdx.x == 0) offsets[n] = carry_s;
}

__global__ void fill_kernel(const int* __restrict__ src, const int* __restrict__ dst,
                            int* __restrict__ cursor, int* __restrict__ csr_src, int E) {
    int e = blockIdx.x * blockDim.x + threadIdx.x;
    if (e < E) {
        int d = dst[e];
        int p = atomicAdd(&cursor[d], 1);
        csr_src[p] = src[e];
    }
}

// ---------------------------------------------------------------------------
// bf16 MFMA GEMM: 64x128 tile, BK=64, 256 thr = 4 waves (2m x 2n),
// each wave 32 rows x 64 cols (acc 2x4). Register staging -> LDS (GLS=72
// pad, 2-way alias free) — the verified template.
// A-staging UNGUARDED: A buffers padded +64 rows (R7, +10us); garbage rows
// only feed write-guarded outputs.
// gemm1 attention epilogue: wave's 64 cols = exactly one head -> pure
// in-wave 16-lane reduce, no LDS combine, no extra barrier.
// C/D: col=lane&15, row=(lane>>4)*4+reg  [verified m89/m91]
// ---------------------------------------------------------------------------
#define GBM 64
#define GBN 128
#define GBK 64
#define GLS 72   // LDS row stride (shorts): 144B; 2-way bank alias = free

__global__ __launch_bounds__(256) void gemm_bf16_kernel(
    const __hip_bfloat16* __restrict__ A,   // [M x K] bf16 row-major (rows padded +64)
    const __hip_bfloat16* __restrict__ BT,  // [N x K] bf16 row-major (B^T)
    const float* __restrict__ bias,         // [N] or null
    __hip_bfloat16* __restrict__ Cb,        // bf16 out
    const float* __restrict__ attS,         // [N] att_src slice or null
    const float* __restrict__ attD,
    float* __restrict__ aS,                 // [M x HEADS] out or null
    float* __restrict__ aD,
    int M, int N, int K, int relu)
{
    __shared__ short As[GBM * GLS];          // 9.2 KB
    __shared__ short Bs[GBN * GLS];          // 18.4 KB
    const int tid = threadIdx.x;
    const int wave = tid >> 6, lane = tid & 63;
    const int lr = lane & 15, lq = lane >> 4;
    const int wm = (wave >> 1) * 32, wn = (wave & 1) * 64;
    const int row0 = blockIdx.x * GBM, col0 = blockIdx.y * GBN;

    const int sra = tid >> 2;             // A staging row 0..63
    const int sca = (tid & 3) * 16;       // shorts: 0,16,32,48
    const int srb = tid >> 1;             // B staging row 0..127
    const int scb = (tid & 1) * 32;       // shorts: 0,32

    f32x4 acc[2][4] = {};

    for (int k0 = 0; k0 < K; k0 += GBK) {
        const __hip_bfloat16* ap = &A[(size_t)(row0 + sra) * K + k0 + sca];
        i32x4 va0 = *(const i32x4*)ap;
        i32x4 va1 = *(const i32x4*)(ap + 8);
        const __hip_bfloat16* bp = &BT[(size_t)(col0 + srb) * K + k0 + scb];
        i32x4 vb0 = *(const i32x4*)bp;
        i32x4 vb1 = *(const i32x4*)(bp + 8);
        i32x4 vb2 = *(const i32x4*)(bp + 16);
        i32x4 vb3 = *(const i32x4*)(bp + 24);
        *(i32x4*)&As[sra * GLS + sca] = va0;
        *(i32x4*)&As[sra * GLS + sca + 8] = va1;
        *(i32x4*)&Bs[srb * GLS + scb] = vb0;
        *(i32x4*)&Bs[srb * GLS + scb + 8] = vb1;
        *(i32x4*)&Bs[srb * GLS + scb + 16] = vb2;
        *(i32x4*)&Bs[srb * GLS + scb + 24] = vb3;
        __syncthreads();

        #pragma unroll
        for (int ks = 0; ks < 2; ++ks) {
            bf16x8_t af[2], bfr[4];
            #pragma unroll
            for (int t = 0; t < 2; ++t)
                af[t]  = *(const bf16x8_t*)&As[(wm + t * 16 + lr) * GLS + ks * 32 + lq * 8];
            #pragma unroll
            for (int t = 0; t < 4; ++t)
                bfr[t] = *(const bf16x8_t*)&Bs[(wn + t * 16 + lr) * GLS + ks * 32 + lq * 8];
            #pragma unroll
            for (int mt = 0; mt < 2; ++mt)
                #pragma unroll
                for (int nt = 0; nt < 4; ++nt)
                    acc[mt][nt] = __builtin_amdgcn_mfma_f32_16x16x32_bf16(
                        af[mt], bfr[nt], acc[mt][nt], 0, 0, 0);
        }
        __syncthreads();
    }

    float bv[4];
    #pragma unroll
    for (int nt = 0; nt < 4; ++nt)
        bv[nt] = bias ? bias[col0 + wn + nt * 16 + lr] : 0.f;

    #pragma unroll
    for (int mt = 0; mt < 2; ++mt) {
        #pragma unroll
        for (int r = 0; r < 4; ++r) {
            int grow = row0 + wm + mt * 16 + lq * 4 + r;
            if (grow >= M) continue;
            #pragma unroll
            for (int nt = 0; nt < 4; ++nt) {
                float v = acc[mt][nt][r] + bv[nt];
                if (relu) v = fmaxf(v, 0.f);
                Cb[(size_t)grow * N + col0 + wn + nt * 16 + lr] = __float2bfloat16(v);
            }
        }
    }

    // Fused attention-coefficient epilogue (gemm1 only).
    // Wave's 64 cols = exactly one head: pure in-wave reduce, no LDS.
    if (aS) {
        const int head = (col0 + wn) >> 6;
        float atS[4], atD[4];
        #pragma unroll
        for (int nt = 0; nt < 4; ++nt) {
            int c = col0 + wn + nt * 16 + lr;
            atS[nt] = attS[c];
            atD[nt] = attD[c];
        }
        #pragma unroll
        for (int mt = 0; mt < 2; ++mt) {
            #pragma unroll
            for (int r = 0; r < 4; ++r) {
                float vs = acc[mt][0][r] * atS[0] + acc[mt][1][r] * atS[1]
                         + acc[mt][2][r] * atS[2] + acc[mt][3][r] * atS[3];
                float vd = acc[mt][0][r] * atD[0] + acc[mt][1][r] * atD[1]
                         + acc[mt][2][r] * atD[2] + acc[mt][3][r] * atD[3];
                #pragma unroll
                for (int off = 1; off < 16; off <<= 1) {
                    vs += __shfl_xor(vs, off);
                    vd += __shfl_xor(vd, off);
                }
                if (lr == 0) {
                    int grow = row0 + wm + mt * 16 + lq * 4 + r;
                    if (grow < M) {
                        aS[grow * HEADS + head] = vs;
                        aD[grow * HEADS + head] = vd;
                    }
                }
            }
        }
    }
}

// ---------------------------------------------------------------------------
// gemm3 + ln2 fused, 512-thread block (R8): C = mid @ w2 + b2; val = C + hb;
// LN; write hb (final layer: split fp32 out).
// Block = 64 rows x 256 cols, 8 waves in 2m x 4n — each wave keeps the
// R5-PROVEN 32x64 / acc 2x4 shape (R6's acc 2x8 regressed on reg pressure;
// this doubles the BLOCK, not the wave). B panel re-staged per 64 rows
// instead of 32 -> per-layer B-staging ~184 MB -> ~82 MB; grid 625 -> 313.
// A-staging unguarded (midb padded +64 rows). LDS 48 KB.
// Row-LN: per-wave 16-lane shfl reduce -> rsum[2][64][4] LDS combine.
// ---------------------------------------------------------------------------
#define FBM 64

__global__ __launch_bounds__(512) void gemm3_ln_kernel(
    const __hip_bfloat16* __restrict__ A,   // midb [M x FF_DIM] (rows padded +64)
    const __hip_bfloat16* __restrict__ BT,  // w2T  [C_DIM x FF_DIM]
    const float* __restrict__ bias,         // b2 [C_DIM]
    const float* __restrict__ ln_g, const float* __restrict__ ln_b,
    __hip_bfloat16* __restrict__ hb,        // residual in; LN out (non-final)
    float* __restrict__ out_split,          // final layer: split fp32 out
    int M)
{
    __shared__ short As[FBM * GLS];         // 9.2 KB
    __shared__ short Bs[C_DIM * GLS];       // 36.9 KB
    __shared__ float rsum[2][FBM][4];       // [s1|s2][row][col-quarter]

    const int tid = threadIdx.x;
    const int wave = tid >> 6, lane = tid & 63;
    const int lr = lane & 15, lq = lane >> 4;
    const int wm = (wave >> 2) * 32;        // row base within tile (0 or 32)
    const int wn = (wave & 3) * 64;         // column base (0,64,128,192)
    const int row0 = blockIdx.x * FBM;

    const int sr = tid >> 3;                // 0..63
    const int sc = (tid & 7) * 8;           // shorts: 0..56

    f32x4 acc[2][4] = {};

    for (int k0 = 0; k0 < FF_DIM; k0 += GBK) {
        // A: 64 rows x 64 shorts, one 16B load/thread (unguarded, padded)
        const __hip_bfloat16* ap = &A[(size_t)(row0 + sr) * FF_DIM + k0 + sc];
        i32x4 va = *(const i32x4*)ap;
        // B: 256 rows x 64 shorts, four 16B loads/thread
        i32x4 vb[4];
        #pragma unroll
        for (int rb = 0; rb < 4; ++rb)
            vb[rb] = *(const i32x4*)&BT[(size_t)(rb * 64 + sr) * FF_DIM + k0 + sc];
        *(i32x4*)&As[sr * GLS + sc] = va;
        #pragma unroll
        for (int rb = 0; rb < 4; ++rb)
            *(i32x4*)&Bs[(rb * 64 + sr) * GLS + sc] = vb[rb];
        __syncthreads();

        #pragma unroll
        for (int ks = 0; ks < 2; ++ks) {
            bf16x8_t af[2], bfr[4];
            #pragma unroll
            for (int mt = 0; mt < 2; ++mt)
                af[mt] = *(const bf16x8_t*)&As[(wm + mt * 16 + lr) * GLS + ks * 32 + lq * 8];
            #pragma unroll
            for (int nt = 0; nt < 4; ++nt)
                bfr[nt] = *(const bf16x8_t*)&Bs[(wn + nt * 16 + lr) * GLS + ks * 32 + lq * 8];
            #pragma unroll
            for (int mt = 0; mt < 2; ++mt)
                #pragma unroll
                for (int nt = 0; nt < 4; ++nt)
                    acc[mt][nt] = __builtin_amdgcn_mfma_f32_16x16x32_bf16(
                        af[mt], bfr[nt], acc[mt][nt], 0, 0, 0);
        }
        __syncthreads();
    }

    float bv[4];
    #pragma unroll
    for (int nt = 0; nt < 4; ++nt)
        bv[nt] = bias[wn + nt * 16 + lr];

    // val = C + b2 + residual; per-row partial sums over this wave's 64 cols
    const unsigned short* hbp = (const unsigned short*)hb;
    #pragma unroll
    for (int mt = 0; mt < 2; ++mt) {
        #pragma unroll
        for (int r = 0; r < 4; ++r) {
            const int rb = wm + mt * 16 + lq * 4 + r;     // 0..63
            const int grow = row0 + rb;
            float s1 = 0.f, s2 = 0.f;
            #pragma unroll
            for (int nt = 0; nt < 4; ++nt) {
                float res = (grow < M)
                    ? bf2f(hbp[(size_t)grow * C_DIM + wn + nt * 16 + lr]) : 0.f;
                float v = acc[mt][nt][r] + bv[nt] + res;
                acc[mt][nt][r] = v;                       // keep for normalize phase
                s1 += v; s2 += v * v;
            }
            #pragma unroll
            for (int off = 1; off < 16; off <<= 1) {
                s1 += __shfl_xor(s1, off);
                s2 += __shfl_xor(s2, off);
            }
            if (lr == 0) {
                rsum[0][rb][wave & 3] = s1;
                rsum[1][rb][wave & 3] = s2;
            }
        }
    }
    __syncthreads();

    float g[4], bb[4];
    #pragma unroll
    for (int nt = 0; nt < 4; ++nt) {
        g[nt]  = ln_g[wn + nt * 16 + lr];
        bb[nt] = ln_b[wn + nt * 16 + lr];
    }

    #pragma unroll
    for (int mt = 0; mt < 2; ++mt) {
        #pragma unroll
        for (int r = 0; r < 4; ++r) {
            const int rb = wm + mt * 16 + lq * 4 + r;
            const int grow = row0 + rb;
            if (grow >= M) continue;
            float s1 = (rsum[0][rb][0] + rsum[0][rb][1]) + (rsum[0][rb][2] + rsum[0][rb][3]);
            float s2 = (rsum[1][rb][0] + rsum[1][rb][1]) + (rsum[1][rb][2] + rsum[1][rb][3]);
            float mean = s1 * (1.0f / C_DIM);
            float inv = rsqrtf(s2 * (1.0f / C_DIM) - mean * mean + LN_EPS);
            if (out_split) {
                #pragma unroll
                for (int nt = 0; nt < 4; ++nt) {
                    float o = (acc[mt][nt][r] - mean) * inv * g[nt] + bb[nt];
                    int c = wn + nt * 16 + lr;
                    size_t off_ = (c < HID) ? ((size_t)grow * HID + c)
                                            : ((size_t)M * HID + (size_t)grow * HID + (c - HID));
                    out_split[off_] = o;
                }
            } else {
                #pragma unroll
                for (int nt = 0; nt < 4; ++nt) {
                    float o = (acc[mt][nt][r] - mean) * inv * g[nt] + bb[nt];
                    ((unsigned short*)hb)[(size_t)grow * C_DIM + wn + nt * 16 + lr] =
                        __bfloat16_as_ushort(__float2bfloat16(o));
                }
            }
        }
    }
}

// ---------------------------------------------------------------------------
// Fused GAT: per-edge exp weights in-loop + weighted bf16 gather + bias +
// residual (bf16 hb) + LN1. One WAVE per node; lane owns 8 channels (16B
// gathers); two 32-lane halves process disjoint edge halves; combined via
// shfl_xor(32). hb updated in place (bf16-only residual stream).
// ---------------------------------------------------------------------------
__global__ __launch_bounds__(256) void agg_kernel(
    const __hip_bfloat16* __restrict__ xhb, const float* __restrict__ a_s,
    const float* __restrict__ a_d, const int* __restrict__ csr,
    const int* __restrict__ offs, const float* __restrict__ gat_b,
    const float* __restrict__ ln_g, const float* __restrict__ ln_b,
    __hip_bfloat16* __restrict__ hb, int Nn)
{
    const int lane = threadIdx.x & 63;
    const int n = __builtin_amdgcn_readfirstlane(blockIdx.x * 4 + (threadIdx.x >> 6));
    if (n >= Nn) return;
    const int half = lane >> 5;
    const int sl = lane & 31;
    const int head = sl >> 3;            // 8 lanes per head
    const int c0 = sl * 8;               // 8 channels per lane
    const unsigned* x = (const unsigned*)xhb;   // packed bf16 pairs
    const size_t rowp = (size_t)n * (C_DIM / 2) + (c0 >> 1);

    const float ad = a_d[n * 4 + head];

    const int beg = offs[n], end = offs[n + 1];
    const int ne = end - beg;
    const int nh0 = (ne + 1) >> 1;
    int ih  = half ? (beg + nh0) : beg;
    int cnt = half ? (ne - nh0) : nh0;

    // residual from bf16 hb (issue early)
    i32x4 rv = *(const i32x4*)&((const unsigned*)hb)[rowp];

    float acc[8] = {};
    float z = 0.f;

    {
        float wself = __expf(leaky(a_s[n * 4 + head] + ad));
        if (half) {
            i32x4 xv = *(const i32x4*)&x[rowp];
            #pragma unroll
            for (int q = 0; q < 4; ++q) {
                float lo, hi; bf2x((unsigned)xv[q], lo, hi);
                acc[2 * q]     = wself * lo;
                acc[2 * q + 1] = wself * hi;
            }
            z = wself;
        }
    }

    for (; cnt >= 4; cnt -= 4, ih += 4) {
        int s0 = csr[ih], s1 = csr[ih + 1], s2 = csr[ih + 2], s3 = csr[ih + 3];
        float w0 = __expf(leaky(a_s[s0 * 4 + head] + ad));
        float w1 = __expf(leaky(a_s[s1 * 4 + head] + ad));
        float w2 = __expf(leaky(a_s[s2 * 4 + head] + ad));
        float w3 = __expf(leaky(a_s[s3 * 4 + head] + ad));
        i32x4 x0 = *(const i32x4*)&x[(size_t)s0 * (C_DIM / 2) + (c0 >> 1)];
        i32x4 x1 = *(const i32x4*)&x[(size_t)s1 * (C_DIM / 2) + (c0 >> 1)];
        i32x4 x2 = *(const i32x4*)&x[(size_t)s2 * (C_DIM / 2) + (c0 >> 1)];
        i32x4 x3 = *(const i32x4*)&x[(size_t)s3 * (C_DIM / 2) + (c0 >> 1)];
        #pragma unroll
        for (int q = 0; q < 4; ++q) {
            float lo, hi;
            bf2x((unsigned)x0[q], lo, hi);
            acc[2 * q] += w0 * lo; acc[2 * q + 1] += w0 * hi;
            bf2x((unsigned)x1[q], lo, hi);
            acc[2 * q] += w1 * lo; acc[2 * q + 1] += w1 * hi;
            bf2x((unsigned)x2[q], lo, hi);
            acc[2 * q] += w2 * lo; acc[2 * q + 1] += w2 * hi;
            bf2x((unsigned)x3[q], lo, hi);
            acc[2 * q] += w3 * lo; acc[2 * q + 1] += w3 * hi;
        }
        z += (w0 + w1) + (w2 + w3);
    }
    for (; cnt > 0; --cnt, ++ih) {
        int s0 = csr[ih];
        float w0 = __expf(leaky(a_s[s0 * 4 + head] + ad));
        i32x4 x0 = *(const i32x4*)&x[(size_t)s0 * (C_DIM / 2) + (c0 >> 1)];
        #pragma unroll
        for (int q = 0; q < 4; ++q) {
            float lo, hi; bf2x((unsigned)x0[q], lo, hi);
            acc[2 * q] += w0 * lo; acc[2 * q + 1] += w0 * hi;
        }
        z += w0;
    }

    #pragma unroll
    for (int j = 0; j < 8; ++j) acc[j] += __shfl_xor(acc[j], 32);
    z += __shfl_xor(z, 32);

    float res[8];
    #pragma unroll
    for (int q = 0; q < 4; ++q) bf2x((unsigned)rv[q], res[2 * q], res[2 * q + 1]);

    float4 gb0 = *(const float4*)&gat_b[c0];
    float4 gb1 = *(const float4*)&gat_b[c0 + 4];
    float gb[8] = {gb0.x, gb0.y, gb0.z, gb0.w, gb1.x, gb1.y, gb1.z, gb1.w};
    float rz = 1.0f / z;
    float val[8];
    #pragma unroll
    for (int j = 0; j < 8; ++j) val[j] = acc[j] * rz + gb[j] + res[j];

    // LN: each channel appears on 2 lanes -> normalize by 512.
    float s1 = 0.f, s2 = 0.f;
    #pragma unroll
    for (int j = 0; j < 8; ++j) { s1 += val[j]; s2 += val[j] * val[j]; }
    #pragma unroll
    for (int off = 1; off < 64; off <<= 1) {
        s1 += __shfl_xor(s1, off);
        s2 += __shfl_xor(s2, off);
    }
    float mean = s1 * (1.0f / (2 * C_DIM));
    float inv = rsqrtf(s2 * (1.0f / (2 * C_DIM)) - mean * mean + LN_EPS);

    if (half == 0) {
        float4 g0 = *(const float4*)&ln_g[c0];
        float4 g1 = *(const float4*)&ln_g[c0 + 4];
        float4 bb0 = *(const float4*)&ln_b[c0];
        float4 bb1 = *(const float4*)&ln_b[c0 + 4];
        float g[8] = {g0.x, g0.y, g0.z, g0.w, g1.x, g1.y, g1.z, g1.w};
        float bb[8] = {bb0.x, bb0.y, bb0.z, bb0.w, bb1.x, bb1.y, bb1.z, bb1.w};
        float o[8];
        #pragma unroll
        for (int j = 0; j < 8; ++j) o[j] = (val[j] - mean) * inv * g[j] + bb[j];
        i32x4 ob;
        ob[0] = (int)packbf(o[0], o[1]);
        ob[1] = (int)packbf(o[2], o[3]);
        ob[2] = (int)packbf(o[4], o[5]);
        ob[3] = (int)packbf(o[6], o[7]);
        *(i32x4*)&((unsigned*)hb)[rowp] = ob;
    }
}

// ---------------------------------------------------------------------------
// Host launch
// ---------------------------------------------------------------------------
extern "C" void kernel_launch(void* const* d_in, const int* in_sizes, int n_in,
                              void* d_out, int out_size, void* d_ws, size_t ws_size,
                              hipStream_t stream)
{
    const float* hf       = (const float*)d_in[0];
    const float* hs       = (const float*)d_in[1];
    const int*   edge     = (const int*)  d_in[2];
    const float* W        = (const float*)d_in[3];
    const float* att_src  = (const float*)d_in[4];
    const float* att_dst  = (const float*)d_in[5];
    const float* gat_b    = (const float*)d_in[6];
    const float* w1       = (const float*)d_in[7];
    const float* b1       = (const float*)d_in[8];
    const float* w2       = (const float*)d_in[9];
    const float* b2       = (const float*)d_in[10];
    const float* ln1g     = (const float*)d_in[11];
    const float* ln1b     = (const float*)d_in[12];
    const float* ln2g     = (const float*)d_in[13];
    const float* ln2b     = (const float*)d_in[14];
    float* out = (float*)d_out;

    const int N = in_sizes[0] / HID;       // 20000
    const int E = in_sizes[2] / 2;         // 320000
    const int* e_src = edge;
    const int* e_dst = edge + E;

    char* p = (char*)d_ws;
    auto alloc = [&](size_t bytes) {
        char* r = p;
        p += (bytes + 255) & ~(size_t)255;
        return (void*)r;
    };
    const int NPAD = N + 64;               // pad: unguarded GEMM A-staging reads past M
    __hip_bfloat16* hb     = (__hip_bfloat16*)alloc((size_t)NPAD * C_DIM * 2);
    __hip_bfloat16* xhb    = (__hip_bfloat16*)alloc((size_t)N * C_DIM * 2);  // gemm1 out
    __hip_bfloat16* midb   = (__hip_bfloat16*)alloc((size_t)NPAD * FF_DIM * 2);
    float*          a_s    = (float*)alloc((size_t)N * HEADS * 4);
    float*          a_d    = (float*)alloc((size_t)N * HEADS * 4);
    int*            counts = (int*)alloc((size_t)N * 4);
    int*            offs   = (int*)alloc((size_t)(N + 1) * 4);
    int*            cursor = (int*)alloc((size_t)N * 4);
    int*            csr    = (int*)alloc((size_t)E * 4);
    __hip_bfloat16* WT     = (__hip_bfloat16*)alloc((size_t)NLAYERS * C_DIM * C_DIM * 2);
    __hip_bfloat16* w1T    = (__hip_bfloat16*)alloc((size_t)NLAYERS * C_DIM * FF_DIM * 2);
    __hip_bfloat16* w2T    = (__hip_bfloat16*)alloc((size_t)NLAYERS * FF_DIM * C_DIM * 2);

    {
        int total = N * C_DIM;
        concat_kernel<<<(total + 255) / 256, 256, 0, stream>>>(hf, hs, hb, N);
    }
    transp_bf16_kernel<<<dim3(C_DIM / 32, C_DIM / 32, NLAYERS), 256, 0, stream>>>(W, WT, C_DIM, C_DIM);
    transp_bf16_kernel<<<dim3(FF_DIM / 32, C_DIM / 32, NLAYERS), 256, 0, stream>>>(w1, w1T, C_DIM, FF_DIM);
    transp_bf16_kernel<<<dim3(C_DIM / 32, FF_DIM / 32, NLAYERS), 256, 0, stream>>>(w2, w2T, FF_DIM, C_DIM);

    zero_i32_kernel<<<(N + 255) / 256, 256, 0, stream>>>(counts, N);
    hist_kernel<<<(E + 255) / 256, 256, 0, stream>>>(e_dst, counts, E);
    scan_kernel<<<1, 1024, 0, stream>>>(counts, offs, cursor, N);
    fill_kernel<<<(E + 255) / 256, 256, 0, stream>>>(e_src, e_dst, cursor, csr, E);

    const int gm = (N + GBM - 1) / GBM;   // 313
    const int gf = (N + FBM - 1) / FBM;   // 313

    for (int l = 0; l < NLAYERS; ++l) {
        const __hip_bfloat16* Wl  = WT  + (size_t)l * C_DIM * C_DIM;
        const __hip_bfloat16* w1l = w1T + (size_t)l * C_DIM * FF_DIM;
        const __hip_bfloat16* w2l = w2T + (size_t)l * FF_DIM * C_DIM;
        const float* asl  = att_src + (size_t)l * C_DIM;
        const float* adl  = att_dst + (size_t)l * C_DIM;
        const float* gbl  = gat_b + (size_t)l * C_DIM;
        const float* b1l  = b1 + (size_t)l * FF_DIM;
        const float* b2l  = b2 + (size_t)l * C_DIM;
        const float* g1l  = ln1g + (size_t)l * C_DIM;
        const float* be1l = ln1b + (size_t)l * C_DIM;
        const float* g2l  = ln2g + (size_t)l * C_DIM;
        const float* be2l = ln2b + (size_t)l * C_DIM;

        // xhb = hb @ W[l] (bf16 out) + fused a_s/a_d epilogue
        gemm_bf16_kernel<<<dim3(gm, C_DIM / GBN), 256, 0, stream>>>(
            hb, Wl, nullptr, xhb, asl, adl, a_s, a_d, N, C_DIM, C_DIM, 0);
        // fused exp-weights + softmax-agg + bias + residual + LN1 (hb in place)
        agg_kernel<<<(N + 3) / 4, 256, 0, stream>>>(
            xhb, a_s, a_d, csr, offs, gbl, g1l, be1l, hb, N);
        // mid = relu(hb @ w1 + b1)  (bf16 out)
        gemm_bf16_kernel<<<dim3(gm, FF_DIM / GBN), 256, 0, stream>>>(
            hb, w1l, b1l, midb, nullptr, nullptr, nullptr, nullptr,
            N, FF_DIM, C_DIM, 1);
        // hb = LN(mid @ w2 + b2 + hb)  [fused gemm3+ln2, 512-thr; final -> out]
        gemm3_ln_kernel<<<gf, 512, 0, stream>>>(
            midb, w2l, b2l, g2l, be2l, hb,
            (l == NLAYERS - 1) ? out : nullptr, N);
    }
}

// Round 9
// 1164.164 us; speedup vs baseline: 1.0073x; 1.0073x over previous
//
#include <hip/hip_runtime.h>
#include <hip/hip_bf16.h>
#include <math.h>

// Problem dims (fixed by reference)
#define C_DIM 256      // h width
#define HID 128
#define HEADS 4
#define OC 64          // per-head out channels
#define FF_DIM 512
#define NLAYERS 12

constexpr float LN_EPS = 1e-5f;
constexpr float SLOPE  = 0.2f;

typedef __attribute__((ext_vector_type(4))) float f32x4;
typedef __attribute__((ext_vector_type(8))) short bf16x8_t;
typedef __attribute__((ext_vector_type(4))) int i32x4;

__device__ __forceinline__ float leaky(float x) { return x > 0.f ? x : SLOPE * x; }

__device__ __forceinline__ float bf2f(unsigned short u) {
    union { unsigned i; float f; } v; v.i = ((unsigned)u) << 16; return v.f;
}
__device__ __forceinline__ void bf2x(unsigned u, float& lo, float& hi) {
    union { unsigned i; float f; } a, b;
    a.i = u << 16; b.i = u & 0xffff0000u;
    lo = a.f; hi = b.f;
}
__device__ __forceinline__ unsigned packbf(float lo, float hi) {
    unsigned a = __bfloat16_as_ushort(__float2bfloat16(lo));
    unsigned b = __bfloat16_as_ushort(__float2bfloat16(hi));
    return a | (b << 16);
}

// ---------------------------------------------------------------------------
// Small utility kernels
// ---------------------------------------------------------------------------
__global__ void zero_i32_kernel(int* __restrict__ p, int n) {
    int i = blockIdx.x * blockDim.x + threadIdx.x;
    if (i < n) p[i] = 0;
}

// bf16-only residual stream: concat writes hb only
__global__ void concat_kernel(const float* __restrict__ hf, const float* __restrict__ hs,
                              __hip_bfloat16* __restrict__ hb, int Nn) {
    int idx = blockIdx.x * blockDim.x + threadIdx.x;
    int total = Nn * C_DIM;
    if (idx < total) {
        int n = idx >> 8;
        int c = idx & 255;
        float v = (c < HID) ? hf[n * HID + c] : hs[n * HID + (c - HID)];
        hb[idx] = __float2bfloat16(v);
    }
}

// Transpose + convert weights: in [L][K][N] fp32 -> out [L][N][K] bf16
__global__ void transp_bf16_kernel(const float* __restrict__ in,
                                   __hip_bfloat16* __restrict__ out, int K, int N) {
    __shared__ float t[32][33];
    const float* inl = in + (size_t)blockIdx.z * K * N;
    __hip_bfloat16* outl = out + (size_t)blockIdx.z * K * N;
    int kb = blockIdx.y * 32, nb = blockIdx.x * 32;
    int tx = threadIdx.x & 31, ty = threadIdx.x >> 5; // 32x8
    #pragma unroll
    for (int r = 0; r < 32; r += 8)
        t[ty + r][tx] = inl[(size_t)(kb + ty + r) * N + nb + tx];
    __syncthreads();
    #pragma unroll
    for (int r = 0; r < 32; r += 8)
        outl[(size_t)(nb + ty + r) * K + kb + tx] = __float2bfloat16(t[tx][ty + r]);
}

// ---------------------------------------------------------------------------
// CSR build: histogram of dst, exclusive scan (wave-shuffle), fill src lists
// ---------------------------------------------------------------------------
__global__ void hist_kernel(const int* __restrict__ dst, int* __restrict__ counts, int E) {
    int e = blockIdx.x * blockDim.x + threadIdx.x;
    if (e < E) atomicAdd(&counts[dst[e]], 1);
}

// single block, 1024 threads = 16 waves. Wave shuffle scan + serial wave-sum scan.
__global__ void scan_kernel(const int* __restrict__ counts, int* __restrict__ offsets,
                            int* __restrict__ cursor, int n) {
    __shared__ int wsum[16];
    __shared__ int carry_s;
    const int lane = threadIdx.x & 63, wid = threadIdx.x >> 6;
    if (threadIdx.x == 0) carry_s = 0;
    __syncthreads();
    for (int base = 0; base < n; base += 1024) {
        int i = base + (int)threadIdx.x;
        int v = (i < n) ? counts[i] : 0;
        int x = v;
        #pragma unroll
        for (int off = 1; off < 64; off <<= 1) {
            int t = __shfl_up(x, off);
            if (lane >= off) x += t;
        }
        if (lane == 63) wsum[wid] = x;
        __syncthreads();
        if (threadIdx.x == 0) {
            int acc = carry_s;
            #pragma unroll
            for (int w = 0; w < 16; ++w) { int t = wsum[w]; wsum[w] = acc; acc += t; }
            carry_s = acc;
        }
        __syncthreads();
        int excl = wsum[wid] + x - v;
        if (i < n) { offsets[i] = excl; cursor[i] = excl; }
        __syncthreads();
    }
    if (threadIdx.x == 0) offsets[n] = carry_s;
}

__global__ void fill_kernel(const int* __restrict__ src, const int* __restrict__ dst,
                            int* __restrict__ cursor, int* __restrict__ csr_src, int E) {
    int e = blockIdx.x * blockDim.x + threadIdx.x;
    if (e < E) {
        int d = dst[e];
        int p = atomicAdd(&cursor[d], 1);
        csr_src[p] = src[e];
    }
}

// ---------------------------------------------------------------------------
// bf16 MFMA GEMM: 64x128 tile, BK=64, K FIXED at 256 (both call sites are
// K=C_DIM) -> compile-time 4-iteration K-loop, fully unrolled: loop overhead
// gone and next iteration's REGISTER staging loads hoist above current MFMA
// phase (legal: they don't touch LDS until after the barrier).
// 256 thr = 4 waves (2m x 2n), each wave 32 rows x 64 cols (acc 2x4).
// Register staging -> LDS (GLS=72 pad, 2-way alias free). A-staging
// UNGUARDED: A buffers padded +64 rows (R7, +10us).
// Geometry is a verified sharp local optimum: 128^2 gl_lds (R0), 2-phase
// dbuf (R3), FBM=64 (R6), 512-thr (R8) all regressed.
// C/D: col=lane&15, row=(lane>>4)*4+reg  [verified m89/m91]
// ---------------------------------------------------------------------------
#define GBM 64
#define GBN 128
#define GBK 64
#define GLS 72   // LDS row stride (shorts): 144B; 2-way bank alias = free

__global__ __launch_bounds__(256) void gemm_bf16_kernel(
    const __hip_bfloat16* __restrict__ A,   // [M x 256] bf16 row-major (rows padded +64)
    const __hip_bfloat16* __restrict__ BT,  // [N x 256] bf16 row-major (B^T)
    const float* __restrict__ bias,         // [N] or null
    __hip_bfloat16* __restrict__ Cb,        // bf16 out
    const float* __restrict__ attS,         // [N] att_src slice or null
    const float* __restrict__ attD,
    float* __restrict__ aS,                 // [M x HEADS] out or null
    float* __restrict__ aD,
    int M, int N, int relu)
{
    constexpr int K = C_DIM;                 // 256: compile-time K
    __shared__ short As[GBM * GLS];          // 9.2 KB
    __shared__ short Bs[GBN * GLS];          // 18.4 KB
    const int tid = threadIdx.x;
    const int wave = tid >> 6, lane = tid & 63;
    const int lr = lane & 15, lq = lane >> 4;
    const int wm = (wave >> 1) * 32, wn = (wave & 1) * 64;
    const int row0 = blockIdx.x * GBM, col0 = blockIdx.y * GBN;

    const int sra = tid >> 2;             // A staging row 0..63
    const int sca = (tid & 3) * 16;       // shorts: 0,16,32,48
    const int srb = tid >> 1;             // B staging row 0..127
    const int scb = (tid & 1) * 32;       // shorts: 0,32

    const __hip_bfloat16* aprow = &A[(size_t)(row0 + sra) * K + sca];
    const __hip_bfloat16* bprow = &BT[(size_t)(col0 + srb) * K + scb];

    f32x4 acc[2][4] = {};

    #pragma unroll
    for (int kc = 0; kc < K / GBK; ++kc) {
        const int k0 = kc * GBK;
        i32x4 va0 = *(const i32x4*)(aprow + k0);
        i32x4 va1 = *(const i32x4*)(aprow + k0 + 8);
        i32x4 vb0 = *(const i32x4*)(bprow + k0);
        i32x4 vb1 = *(const i32x4*)(bprow + k0 + 8);
        i32x4 vb2 = *(const i32x4*)(bprow + k0 + 16);
        i32x4 vb3 = *(const i32x4*)(bprow + k0 + 24);
        *(i32x4*)&As[sra * GLS + sca] = va0;
        *(i32x4*)&As[sra * GLS + sca + 8] = va1;
        *(i32x4*)&Bs[srb * GLS + scb] = vb0;
        *(i32x4*)&Bs[srb * GLS + scb + 8] = vb1;
        *(i32x4*)&Bs[srb * GLS + scb + 16] = vb2;
        *(i32x4*)&Bs[srb * GLS + scb + 24] = vb3;
        __syncthreads();

        #pragma unroll
        for (int ks = 0; ks < 2; ++ks) {
            bf16x8_t af[2], bfr[4];
            #pragma unroll
            for (int t = 0; t < 2; ++t)
                af[t]  = *(const bf16x8_t*)&As[(wm + t * 16 + lr) * GLS + ks * 32 + lq * 8];
            #pragma unroll
            for (int t = 0; t < 4; ++t)
                bfr[t] = *(const bf16x8_t*)&Bs[(wn + t * 16 + lr) * GLS + ks * 32 + lq * 8];
            #pragma unroll
            for (int mt = 0; mt < 2; ++mt)
                #pragma unroll
                for (int nt = 0; nt < 4; ++nt)
                    acc[mt][nt] = __builtin_amdgcn_mfma_f32_16x16x32_bf16(
                        af[mt], bfr[nt], acc[mt][nt], 0, 0, 0);
        }
        if (kc + 1 < K / GBK) __syncthreads();
    }

    float bv[4];
    #pragma unroll
    for (int nt = 0; nt < 4; ++nt)
        bv[nt] = bias ? bias[col0 + wn + nt * 16 + lr] : 0.f;

    #pragma unroll
    for (int mt = 0; mt < 2; ++mt) {
        #pragma unroll
        for (int r = 0; r < 4; ++r) {
            int grow = row0 + wm + mt * 16 + lq * 4 + r;
            if (grow >= M) continue;
            #pragma unroll
            for (int nt = 0; nt < 4; ++nt) {
                float v = acc[mt][nt][r] + bv[nt];
                if (relu) v = fmaxf(v, 0.f);
                Cb[(size_t)grow * N + col0 + wn + nt * 16 + lr] = __float2bfloat16(v);
            }
        }
    }

    // Fused attention-coefficient epilogue (gemm1 only).
    // Wave's 64 cols = exactly one head: pure in-wave reduce, no LDS.
    if (aS) {
        const int head = (col0 + wn) >> 6;
        float atS[4], atD[4];
        #pragma unroll
        for (int nt = 0; nt < 4; ++nt) {
            int c = col0 + wn + nt * 16 + lr;
            atS[nt] = attS[c];
            atD[nt] = attD[c];
        }
        #pragma unroll
        for (int mt = 0; mt < 2; ++mt) {
            #pragma unroll
            for (int r = 0; r < 4; ++r) {
                float vs = acc[mt][0][r] * atS[0] + acc[mt][1][r] * atS[1]
                         + acc[mt][2][r] * atS[2] + acc[mt][3][r] * atS[3];
                float vd = acc[mt][0][r] * atD[0] + acc[mt][1][r] * atD[1]
                         + acc[mt][2][r] * atD[2] + acc[mt][3][r] * atD[3];
                #pragma unroll
                for (int off = 1; off < 16; off <<= 1) {
                    vs += __shfl_xor(vs, off);
                    vd += __shfl_xor(vd, off);
                }
                if (lr == 0) {
                    int grow = row0 + wm + mt * 16 + lq * 4 + r;
                    if (grow < M) {
                        aS[grow * HEADS + head] = vs;
                        aD[grow * HEADS + head] = vd;
                    }
                }
            }
        }
    }
}

// ---------------------------------------------------------------------------
// gemm3 + ln2 fused (R7-verified, FBM=32, 256 thr): fbuf-free.
// C = mid @ w2 + b2; val = C + hb; LN; write hb (final layer: split fp32).
// Block = 32 rows x 256 cols (full N), K=512 (compile-time), grid 625.
// 4 waves split columns; acc 2x4 = 32 VGPRs. (FBM=64 R6 and 512-thr R8
// variants both regressed — geometry is a sharp local optimum.)
// Row-LN: per-wave 16-lane shfl reduce -> 1KB LDS combine of 4 col-quarters.
// ---------------------------------------------------------------------------
#define FBM 32

__global__ __launch_bounds__(256) void gemm3_ln_kernel(
    const __hip_bfloat16* __restrict__ A,   // midb [M x FF_DIM]
    const __hip_bfloat16* __restrict__ BT,  // w2T  [C_DIM x FF_DIM]
    const float* __restrict__ bias,         // b2 [C_DIM]
    const float* __restrict__ ln_g, const float* __restrict__ ln_b,
    __hip_bfloat16* __restrict__ hb,        // residual in; LN out (non-final)
    float* __restrict__ out_split,          // final layer: split fp32 out
    int M)
{
    __shared__ short As[FBM * GLS];         // 4.5 KB
    __shared__ short Bs[C_DIM * GLS];       // 36 KB
    __shared__ float rsum[2][FBM][4];       // [s1|s2][row][col-quarter]

    const int tid = threadIdx.x;
    const int wave = tid >> 6, lane = tid & 63;
    const int lr = lane & 15, lq = lane >> 4;
    const int wn = wave * 64;               // column base for this wave
    const int row0 = blockIdx.x * FBM;

    const int sr = tid >> 2;                // 0..63
    const int sc = (tid & 3) * 16;

    f32x4 acc[2][4] = {};

    #pragma unroll
    for (int kc = 0; kc < FF_DIM / GBK; ++kc) {
        const int k0 = kc * GBK;
        if (sr < FBM) {
            const __hip_bfloat16* ap = &A[(size_t)(row0 + sr) * FF_DIM + k0 + sc];
            *(i32x4*)&As[sr * GLS + sc] = *(const i32x4*)ap;
            *(i32x4*)&As[sr * GLS + sc + 8] = *(const i32x4*)(ap + 8);
        }
        #pragma unroll
        for (int rb = 0; rb < 4; ++rb) {
            const int br = rb * 64 + sr;
            const __hip_bfloat16* bp = &BT[(size_t)br * FF_DIM + k0 + sc];
            *(i32x4*)&Bs[br * GLS + sc] = *(const i32x4*)bp;
            *(i32x4*)&Bs[br * GLS + sc + 8] = *(const i32x4*)(bp + 8);
        }
        __syncthreads();

        #pragma unroll
        for (int ks = 0; ks < 2; ++ks) {
            bf16x8_t af[2], bfr[4];
            #pragma unroll
            for (int mt = 0; mt < 2; ++mt)
                af[mt] = *(const bf16x8_t*)&As[(mt * 16 + lr) * GLS + ks * 32 + lq * 8];
            #pragma unroll
            for (int nt = 0; nt < 4; ++nt)
                bfr[nt] = *(const bf16x8_t*)&Bs[(wn + nt * 16 + lr) * GLS + ks * 32 + lq * 8];
            #pragma unroll
            for (int mt = 0; mt < 2; ++mt)
                #pragma unroll
                for (int nt = 0; nt < 4; ++nt)
                    acc[mt][nt] = __builtin_amdgcn_mfma_f32_16x16x32_bf16(
                        af[mt], bfr[nt], acc[mt][nt], 0, 0, 0);
        }
        if (kc + 1 < FF_DIM / GBK) __syncthreads();
    }

    float bv[4];
    #pragma unroll
    for (int nt = 0; nt < 4; ++nt)
        bv[nt] = bias[wn + nt * 16 + lr];

    // val = C + b2 + residual; per-row partial sums over this wave's 64 cols
    const unsigned short* hbp = (const unsigned short*)hb;
    #pragma unroll
    for (int mt = 0; mt < 2; ++mt) {
        #pragma unroll
        for (int r = 0; r < 4; ++r) {
            const int rb = mt * 16 + lq * 4 + r;      // 0..31
            const int grow = row0 + rb;
            float s1 = 0.f, s2 = 0.f;
            #pragma unroll
            for (int nt = 0; nt < 4; ++nt) {
                float res = (grow < M)
                    ? bf2f(hbp[(size_t)grow * C_DIM + wn + nt * 16 + lr]) : 0.f;
                float v = acc[mt][nt][r] + bv[nt] + res;
                acc[mt][nt][r] = v;                   // keep for normalize phase
                s1 += v; s2 += v * v;
            }
            #pragma unroll
            for (int off = 1; off < 16; off <<= 1) {
                s1 += __shfl_xor(s1, off);
                s2 += __shfl_xor(s2, off);
            }
            if (lr == 0) {
                rsum[0][rb][wave] = s1;
                rsum[1][rb][wave] = s2;
            }
        }
    }
    __syncthreads();

    float g[4], bb[4];
    #pragma unroll
    for (int nt = 0; nt < 4; ++nt) {
        g[nt]  = ln_g[wn + nt * 16 + lr];
        bb[nt] = ln_b[wn + nt * 16 + lr];
    }

    #pragma unroll
    for (int mt = 0; mt < 2; ++mt) {
        #pragma unroll
        for (int r = 0; r < 4; ++r) {
            const int rb = mt * 16 + lq * 4 + r;
            const int grow = row0 + rb;
            if (grow >= M) continue;
            float s1 = (rsum[0][rb][0] + rsum[0][rb][1]) + (rsum[0][rb][2] + rsum[0][rb][3]);
            float s2 = (rsum[1][rb][0] + rsum[1][rb][1]) + (rsum[1][rb][2] + rsum[1][rb][3]);
            float mean = s1 * (1.0f / C_DIM);
            float inv = rsqrtf(s2 * (1.0f / C_DIM) - mean * mean + LN_EPS);
            if (out_split) {
                #pragma unroll
                for (int nt = 0; nt < 4; ++nt) {
                    float o = (acc[mt][nt][r] - mean) * inv * g[nt] + bb[nt];
                    int c = wn + nt * 16 + lr;
                    size_t off_ = (c < HID) ? ((size_t)grow * HID + c)
                                            : ((size_t)M * HID + (size_t)grow * HID + (c - HID));
                    out_split[off_] = o;
                }
            } else {
                #pragma unroll
                for (int nt = 0; nt < 4; ++nt) {
                    float o = (acc[mt][nt][r] - mean) * inv * g[nt] + bb[nt];
                    ((unsigned short*)hb)[(size_t)grow * C_DIM + wn + nt * 16 + lr] =
                        __bfloat16_as_ushort(__float2bfloat16(o));
                }
            }
        }
    }
}

// ---------------------------------------------------------------------------
// Fused GAT: per-edge exp weights in-loop + weighted bf16 gather + bias +
// residual (bf16 hb) + LN1. One WAVE per node; lane owns 8 channels (16B
// gathers); two 32-lane halves process disjoint edge halves; combined via
// shfl_xor(32). hb updated in place (bf16-only residual stream).
// ---------------------------------------------------------------------------
__global__ __launch_bounds__(256) void agg_kernel(
    const __hip_bfloat16* __restrict__ xhb, const float* __restrict__ a_s,
    const float* __restrict__ a_d, const int* __restrict__ csr,
    const int* __restrict__ offs, const float* __restrict__ gat_b,
    const float* __restrict__ ln_g, const float* __restrict__ ln_b,
    __hip_bfloat16* __restrict__ hb, int Nn)
{
    const int lane = threadIdx.x & 63;
    const int n = __builtin_amdgcn_readfirstlane(blockIdx.x * 4 + (threadIdx.x >> 6));
    if (n >= Nn) return;
    const int half = lane >> 5;
    const int sl = lane & 31;
    const int head = sl >> 3;            // 8 lanes per head
    const int c0 = sl * 8;               // 8 channels per lane
    const unsigned* x = (const unsigned*)xhb;   // packed bf16 pairs
    const size_t rowp = (size_t)n * (C_DIM / 2) + (c0 >> 1);

    const float ad = a_d[n * 4 + head];

    const int beg = offs[n], end = offs[n + 1];
    const int ne = end - beg;
    const int nh0 = (ne + 1) >> 1;
    int ih  = half ? (beg + nh0) : beg;
    int cnt = half ? (ne - nh0) : nh0;

    // residual from bf16 hb (issue early)
    i32x4 rv = *(const i32x4*)&((const unsigned*)hb)[rowp];

    float acc[8] = {};
    float z = 0.f;

    {
        float wself = __expf(leaky(a_s[n * 4 + head] + ad));
        if (half) {
            i32x4 xv = *(const i32x4*)&x[rowp];
            #pragma unroll
            for (int q = 0; q < 4; ++q) {
                float lo, hi; bf2x((unsigned)xv[q], lo, hi);
                acc[2 * q]     = wself * lo;
                acc[2 * q + 1] = wself * hi;
            }
            z = wself;
        }
    }

    for (; cnt >= 4; cnt -= 4, ih += 4) {
        int s0 = csr[ih], s1 = csr[ih + 1], s2 = csr[ih + 2], s3 = csr[ih + 3];
        float w0 = __expf(leaky(a_s[s0 * 4 + head] + ad));
        float w1 = __expf(leaky(a_s[s1 * 4 + head] + ad));
        float w2 = __expf(leaky(a_s[s2 * 4 + head] + ad));
        float w3 = __expf(leaky(a_s[s3 * 4 + head] + ad));
        i32x4 x0 = *(const i32x4*)&x[(size_t)s0 * (C_DIM / 2) + (c0 >> 1)];
        i32x4 x1 = *(const i32x4*)&x[(size_t)s1 * (C_DIM / 2) + (c0 >> 1)];
        i32x4 x2 = *(const i32x4*)&x[(size_t)s2 * (C_DIM / 2) + (c0 >> 1)];
        i32x4 x3 = *(const i32x4*)&x[(size_t)s3 * (C_DIM / 2) + (c0 >> 1)];
        #pragma unroll
        for (int q = 0; q < 4; ++q) {
            float lo, hi;
            bf2x((unsigned)x0[q], lo, hi);
            acc[2 * q] += w0 * lo; acc[2 * q + 1] += w0 * hi;
            bf2x((unsigned)x1[q], lo, hi);
            acc[2 * q] += w1 * lo; acc[2 * q + 1] += w1 * hi;
            bf2x((unsigned)x2[q], lo, hi);
            acc[2 * q] += w2 * lo; acc[2 * q + 1] += w2 * hi;
            bf2x((unsigned)x3[q], lo, hi);
            acc[2 * q] += w3 * lo; acc[2 * q + 1] += w3 * hi;
        }
        z += (w0 + w1) + (w2 + w3);
    }
    for (; cnt > 0; --cnt, ++ih) {
        int s0 = csr[ih];
        float w0 = __expf(leaky(a_s[s0 * 4 + head] + ad));
        i32x4 x0 = *(const i32x4*)&x[(size_t)s0 * (C_DIM / 2) + (c0 >> 1)];
        #pragma unroll
        for (int q = 0; q < 4; ++q) {
            float lo, hi; bf2x((unsigned)x0[q], lo, hi);
            acc[2 * q] += w0 * lo; acc[2 * q + 1] += w0 * hi;
        }
        z += w0;
    }

    #pragma unroll
    for (int j = 0; j < 8; ++j) acc[j] += __shfl_xor(acc[j], 32);
    z += __shfl_xor(z, 32);

    float res[8];
    #pragma unroll
    for (int q = 0; q < 4; ++q) bf2x((unsigned)rv[q], res[2 * q], res[2 * q + 1]);

    float4 gb0 = *(const float4*)&gat_b[c0];
    float4 gb1 = *(const float4*)&gat_b[c0 + 4];
    float gb[8] = {gb0.x, gb0.y, gb0.z, gb0.w, gb1.x, gb1.y, gb1.z, gb1.w};
    float rz = 1.0f / z;
    float val[8];
    #pragma unroll
    for (int j = 0; j < 8; ++j) val[j] = acc[j] * rz + gb[j] + res[j];

    // LN: each channel appears on 2 lanes -> normalize by 512.
    float s1 = 0.f, s2 = 0.f;
    #pragma unroll
    for (int j = 0; j < 8; ++j) { s1 += val[j]; s2 += val[j] * val[j]; }
    #pragma unroll
    for (int off = 1; off < 64; off <<= 1) {
        s1 += __shfl_xor(s1, off);
        s2 += __shfl_xor(s2, off);
    }
    float mean = s1 * (1.0f / (2 * C_DIM));
    float inv = rsqrtf(s2 * (1.0f / (2 * C_DIM)) - mean * mean + LN_EPS);

    if (half == 0) {
        float4 g0 = *(const float4*)&ln_g[c0];
        float4 g1 = *(const float4*)&ln_g[c0 + 4];
        float4 bb0 = *(const float4*)&ln_b[c0];
        float4 bb1 = *(const float4*)&ln_b[c0 + 4];
        float g[8] = {g0.x, g0.y, g0.z, g0.w, g1.x, g1.y, g1.z, g1.w};
        float bb[8] = {bb0.x, bb0.y, bb0.z, bb0.w, bb1.x, bb1.y, bb1.z, bb1.w};
        float o[8];
        #pragma unroll
        for (int j = 0; j < 8; ++j) o[j] = (val[j] - mean) * inv * g[j] + bb[j];
        i32x4 ob;
        ob[0] = (int)packbf(o[0], o[1]);
        ob[1] = (int)packbf(o[2], o[3]);
        ob[2] = (int)packbf(o[4], o[5]);
        ob[3] = (int)packbf(o[6], o[7]);
        *(i32x4*)&((unsigned*)hb)[rowp] = ob;
    }
}

// ---------------------------------------------------------------------------
// Host launch
// ---------------------------------------------------------------------------
extern "C" void kernel_launch(void* const* d_in, const int* in_sizes, int n_in,
                              void* d_out, int out_size, void* d_ws, size_t ws_size,
                              hipStream_t stream)
{
    const float* hf       = (const float*)d_in[0];
    const float* hs       = (const float*)d_in[1];
    const int*   edge     = (const int*)  d_in[2];
    const float* W        = (const float*)d_in[3];
    const float* att_src  = (const float*)d_in[4];
    const float* att_dst  = (const float*)d_in[5];
    const float* gat_b    = (const float*)d_in[6];
    const float* w1       = (const float*)d_in[7];
    const float* b1       = (const float*)d_in[8];
    const float* w2       = (const float*)d_in[9];
    const float* b2       = (const float*)d_in[10];
    const float* ln1g     = (const float*)d_in[11];
    const float* ln1b     = (const float*)d_in[12];
    const float* ln2g     = (const float*)d_in[13];
    const float* ln2b     = (const float*)d_in[14];
    float* out = (float*)d_out;

    const int N = in_sizes[0] / HID;       // 20000
    const int E = in_sizes[2] / 2;         // 320000
    const int* e_src = edge;
    const int* e_dst = edge + E;

    char* p = (char*)d_ws;
    auto alloc = [&](size_t bytes) {
        char* r = p;
        p += (bytes + 255) & ~(size_t)255;
        return (void*)r;
    };
    const int NPAD = N + 64;               // pad: unguarded GEMM A-staging reads past M
    __hip_bfloat16* hb     = (__hip_bfloat16*)alloc((size_t)NPAD * C_DIM * 2);
    __hip_bfloat16* xhb    = (__hip_bfloat16*)alloc((size_t)N * C_DIM * 2);  // gemm1 out
    __hip_bfloat16* midb   = (__hip_bfloat16*)alloc((size_t)N * FF_DIM * 2);
    float*          a_s    = (float*)alloc((size_t)N * HEADS * 4);
    float*          a_d    = (float*)alloc((size_t)N * HEADS * 4);
    int*            counts = (int*)alloc((size_t)N * 4);
    int*            offs   = (int*)alloc((size_t)(N + 1) * 4);
    int*            cursor = (int*)alloc((size_t)N * 4);
    int*            csr    = (int*)alloc((size_t)E * 4);
    __hip_bfloat16* WT     = (__hip_bfloat16*)alloc((size_t)NLAYERS * C_DIM * C_DIM * 2);
    __hip_bfloat16* w1T    = (__hip_bfloat16*)alloc((size_t)NLAYERS * C_DIM * FF_DIM * 2);
    __hip_bfloat16* w2T    = (__hip_bfloat16*)alloc((size_t)NLAYERS * FF_DIM * C_DIM * 2);

    {
        int total = N * C_DIM;
        concat_kernel<<<(total + 255) / 256, 256, 0, stream>>>(hf, hs, hb, N);
    }
    transp_bf16_kernel<<<dim3(C_DIM / 32, C_DIM / 32, NLAYERS), 256, 0, stream>>>(W, WT, C_DIM, C_DIM);
    transp_bf16_kernel<<<dim3(FF_DIM / 32, C_DIM / 32, NLAYERS), 256, 0, stream>>>(w1, w1T, C_DIM, FF_DIM);
    transp_bf16_kernel<<<dim3(C_DIM / 32, FF_DIM / 32, NLAYERS), 256, 0, stream>>>(w2, w2T, FF_DIM, C_DIM);

    zero_i32_kernel<<<(N + 255) / 256, 256, 0, stream>>>(counts, N);
    hist_kernel<<<(E + 255) / 256, 256, 0, stream>>>(e_dst, counts, E);
    scan_kernel<<<1, 1024, 0, stream>>>(counts, offs, cursor, N);
    fill_kernel<<<(E + 255) / 256, 256, 0, stream>>>(e_src, e_dst, cursor, csr, E);

    const int gm = (N + GBM - 1) / GBM;   // 313
    const int gf = (N + FBM - 1) / FBM;   // 625

    for (int l = 0; l < NLAYERS; ++l) {
        const __hip_bfloat16* Wl  = WT  + (size_t)l * C_DIM * C_DIM;
        const __hip_bfloat16* w1l = w1T + (size_t)l * C_DIM * FF_DIM;
        const __hip_bfloat16* w2l = w2T + (size_t)l * FF_DIM * C_DIM;
        const float* asl  = att_src + (size_t)l * C_DIM;
        const float* adl  = att_dst + (size_t)l * C_DIM;
        const float* gbl  = gat_b + (size_t)l * C_DIM;
        const float* b1l  = b1 + (size_t)l * FF_DIM;
        const float* b2l  = b2 + (size_t)l * C_DIM;
        const float* g1l  = ln1g + (size_t)l * C_DIM;
        const float* be1l = ln1b + (size_t)l * C_DIM;
        const float* g2l  = ln2g + (size_t)l * C_DIM;
        const float* be2l = ln2b + (size_t)l * C_DIM;

        // xhb = hb @ W[l] (bf16 out) + fused a_s/a_d epilogue
        gemm_bf16_kernel<<<dim3(gm, C_DIM / GBN), 256, 0, stream>>>(
            hb, Wl, nullptr, xhb, asl, adl, a_s, a_d, N, C_DIM, 0);
        // fused exp-weights + softmax-agg + bias + residual + LN1 (hb in place)
        agg_kernel<<<(N + 3) / 4, 256, 0, stream>>>(
            xhb, a_s, a_d, csr, offs, gbl, g1l, be1l, hb, N);
        // mid = relu(hb @ w1 + b1)  (bf16 out)
        gemm_bf16_kernel<<<dim3(gm, FF_DIM / GBN), 256, 0, stream>>>(
            hb, w1l, b1l, midb, nullptr, nullptr, nullptr, nullptr,
            N, FF_DIM, 1);
        // hb = LN(mid @ w2 + b2 + hb)  [fused gemm3+ln2; final layer -> out]
        gemm3_ln_kernel<<<gf, 256, 0, stream>>>(
            midb, w2l, b2l, g2l, be2l, hb,
            (l == NLAYERS - 1) ? out : nullptr, N);
    }
}

// Round 10
// 1147.310 us; speedup vs baseline: 1.0221x; 1.0147x over previous
//
#include <hip/hip_runtime.h>
#include <hip/hip_bf16.h>
#include <math.h>

// Problem dims (fixed by reference)
#define C_DIM 256      // h width
#define HID 128
#define HEADS 4
#define OC 64          // per-head out channels
#define FF_DIM 512
#define NLAYERS 12

constexpr float LN_EPS = 1e-5f;
constexpr float SLOPE  = 0.2f;

typedef __attribute__((ext_vector_type(4))) float f32x4;
typedef __attribute__((ext_vector_type(8))) short bf16x8_t;
typedef __attribute__((ext_vector_type(4))) int i32x4;

__device__ __forceinline__ float leaky(float x) { return x > 0.f ? x : SLOPE * x; }

__device__ __forceinline__ float bf2f(unsigned short u) {
    union { unsigned i; float f; } v; v.i = ((unsigned)u) << 16; return v.f;
}
__device__ __forceinline__ void bf2x(unsigned u, float& lo, float& hi) {
    union { unsigned i; float f; } a, b;
    a.i = u << 16; b.i = u & 0xffff0000u;
    lo = a.f; hi = b.f;
}
__device__ __forceinline__ unsigned packbf(float lo, float hi) {
    unsigned a = __bfloat16_as_ushort(__float2bfloat16(lo));
    unsigned b = __bfloat16_as_ushort(__float2bfloat16(hi));
    return a | (b << 16);
}

// ---------------------------------------------------------------------------
// Small utility kernels
// ---------------------------------------------------------------------------
__global__ void zero_i32_kernel(int* __restrict__ p, int n) {
    int i = blockIdx.x * blockDim.x + threadIdx.x;
    if (i < n) p[i] = 0;
}

// bf16-only residual stream: concat writes hb only
__global__ void concat_kernel(const float* __restrict__ hf, const float* __restrict__ hs,
                              __hip_bfloat16* __restrict__ hb, int Nn) {
    int idx = blockIdx.x * blockDim.x + threadIdx.x;
    int total = Nn * C_DIM;
    if (idx < total) {
        int n = idx >> 8;
        int c = idx & 255;
        float v = (c < HID) ? hf[n * HID + c] : hs[n * HID + (c - HID)];
        hb[idx] = __float2bfloat16(v);
    }
}

// Transpose + convert weights: in [L][K][N] fp32 -> out [L][N][K] bf16
__global__ void transp_bf16_kernel(const float* __restrict__ in,
                                   __hip_bfloat16* __restrict__ out, int K, int N) {
    __shared__ float t[32][33];
    const float* inl = in + (size_t)blockIdx.z * K * N;
    __hip_bfloat16* outl = out + (size_t)blockIdx.z * K * N;
    int kb = blockIdx.y * 32, nb = blockIdx.x * 32;
    int tx = threadIdx.x & 31, ty = threadIdx.x >> 5; // 32x8
    #pragma unroll
    for (int r = 0; r < 32; r += 8)
        t[ty + r][tx] = inl[(size_t)(kb + ty + r) * N + nb + tx];
    __syncthreads();
    #pragma unroll
    for (int r = 0; r < 32; r += 8)
        outl[(size_t)(nb + ty + r) * K + kb + tx] = __float2bfloat16(t[tx][ty + r]);
}

// ---------------------------------------------------------------------------
// CSR build: histogram of dst, exclusive scan (wave-shuffle), fill src lists
// ---------------------------------------------------------------------------
__global__ void hist_kernel(const int* __restrict__ dst, int* __restrict__ counts, int E) {
    int e = blockIdx.x * blockDim.x + threadIdx.x;
    if (e < E) atomicAdd(&counts[dst[e]], 1);
}

// single block, 1024 threads = 16 waves. Wave shuffle scan + serial wave-sum scan.
__global__ void scan_kernel(const int* __restrict__ counts, int* __restrict__ offsets,
                            int* __restrict__ cursor, int n) {
    __shared__ int wsum[16];
    __shared__ int carry_s;
    const int lane = threadIdx.x & 63, wid = threadIdx.x >> 6;
    if (threadIdx.x == 0) carry_s = 0;
    __syncthreads();
    for (int base = 0; base < n; base += 1024) {
        int i = base + (int)threadIdx.x;
        int v = (i < n) ? counts[i] : 0;
        int x = v;
        #pragma unroll
        for (int off = 1; off < 64; off <<= 1) {
            int t = __shfl_up(x, off);
            if (lane >= off) x += t;
        }
        if (lane == 63) wsum[wid] = x;
        __syncthreads();
        if (threadIdx.x == 0) {
            int acc = carry_s;
            #pragma unroll
            for (int w = 0; w < 16; ++w) { int t = wsum[w]; wsum[w] = acc; acc += t; }
            carry_s = acc;
        }
        __syncthreads();
        int excl = wsum[wid] + x - v;
        if (i < n) { offsets[i] = excl; cursor[i] = excl; }
        __syncthreads();
    }
    if (threadIdx.x == 0) offsets[n] = carry_s;
}

__global__ void fill_kernel(const int* __restrict__ src, const int* __restrict__ dst,
                            int* __restrict__ cursor, int* __restrict__ csr_src, int E) {
    int e = blockIdx.x * blockDim.x + threadIdx.x;
    if (e < E) {
        int d = dst[e];
        int p = atomicAdd(&cursor[d], 1);
        csr_src[p] = src[e];
    }
}

// ---------------------------------------------------------------------------
// bf16 MFMA GEMM (R7-verified, 1134.7us state): 64x128 tile, BK=64, 256 thr
// = 4 waves (2m x 2n), each wave 32 rows x 64 cols (acc 2x4). Register
// staging -> LDS (GLS=72 pad, 2-way alias free). A-staging UNGUARDED: A
// buffers padded +64 rows (R7, +10us). Runtime K loop (R9's full unroll
// REGRESSED: hoisted multi-iteration staging loads -> reg pressure).
// Geometry is a sharp local optimum: 128^2 gl_lds (R0), 2-phase dbuf (R3),
// FBM=64 (R6), 512-thr (R8), K-unroll (R9) all regressed.
// gemm1 attention epilogue: wave's 64 cols = exactly one head -> pure
// in-wave 16-lane reduce, no LDS combine, no extra barrier.
// C/D: col=lane&15, row=(lane>>4)*4+reg  [verified m89/m91]
// ---------------------------------------------------------------------------
#define GBM 64
#define GBN 128
#define GBK 64
#define GLS 72   // LDS row stride (shorts): 144B; 2-way bank alias = free

__global__ __launch_bounds__(256) void gemm_bf16_kernel(
    const __hip_bfloat16* __restrict__ A,   // [M x K] bf16 row-major (rows padded +64)
    const __hip_bfloat16* __restrict__ BT,  // [N x K] bf16 row-major (B^T)
    const float* __restrict__ bias,         // [N] or null
    __hip_bfloat16* __restrict__ Cb,        // bf16 out
    const float* __restrict__ attS,         // [N] att_src slice or null
    const float* __restrict__ attD,
    float* __restrict__ aS,                 // [M x HEADS] out or null
    float* __restrict__ aD,
    int M, int N, int K, int relu)
{
    __shared__ short As[GBM * GLS];          // 9.2 KB
    __shared__ short Bs[GBN * GLS];          // 18.4 KB
    const int tid = threadIdx.x;
    const int wave = tid >> 6, lane = tid & 63;
    const int lr = lane & 15, lq = lane >> 4;
    const int wm = (wave >> 1) * 32, wn = (wave & 1) * 64;
    const int row0 = blockIdx.x * GBM, col0 = blockIdx.y * GBN;

    const int sra = tid >> 2;             // A staging row 0..63
    const int sca = (tid & 3) * 16;       // shorts: 0,16,32,48
    const int srb = tid >> 1;             // B staging row 0..127
    const int scb = (tid & 1) * 32;       // shorts: 0,32

    f32x4 acc[2][4] = {};

    for (int k0 = 0; k0 < K; k0 += GBK) {
        const __hip_bfloat16* ap = &A[(size_t)(row0 + sra) * K + k0 + sca];
        i32x4 va0 = *(const i32x4*)ap;
        i32x4 va1 = *(const i32x4*)(ap + 8);
        const __hip_bfloat16* bp = &BT[(size_t)(col0 + srb) * K + k0 + scb];
        i32x4 vb0 = *(const i32x4*)bp;
        i32x4 vb1 = *(const i32x4*)(bp + 8);
        i32x4 vb2 = *(const i32x4*)(bp + 16);
        i32x4 vb3 = *(const i32x4*)(bp + 24);
        *(i32x4*)&As[sra * GLS + sca] = va0;
        *(i32x4*)&As[sra * GLS + sca + 8] = va1;
        *(i32x4*)&Bs[srb * GLS + scb] = vb0;
        *(i32x4*)&Bs[srb * GLS + scb + 8] = vb1;
        *(i32x4*)&Bs[srb * GLS + scb + 16] = vb2;
        *(i32x4*)&Bs[srb * GLS + scb + 24] = vb3;
        __syncthreads();

        #pragma unroll
        for (int ks = 0; ks < 2; ++ks) {
            bf16x8_t af[2], bfr[4];
            #pragma unroll
            for (int t = 0; t < 2; ++t)
                af[t]  = *(const bf16x8_t*)&As[(wm + t * 16 + lr) * GLS + ks * 32 + lq * 8];
            #pragma unroll
            for (int t = 0; t < 4; ++t)
                bfr[t] = *(const bf16x8_t*)&Bs[(wn + t * 16 + lr) * GLS + ks * 32 + lq * 8];
            #pragma unroll
            for (int mt = 0; mt < 2; ++mt)
                #pragma unroll
                for (int nt = 0; nt < 4; ++nt)
                    acc[mt][nt] = __builtin_amdgcn_mfma_f32_16x16x32_bf16(
                        af[mt], bfr[nt], acc[mt][nt], 0, 0, 0);
        }
        __syncthreads();
    }

    float bv[4];
    #pragma unroll
    for (int nt = 0; nt < 4; ++nt)
        bv[nt] = bias ? bias[col0 + wn + nt * 16 + lr] : 0.f;

    #pragma unroll
    for (int mt = 0; mt < 2; ++mt) {
        #pragma unroll
        for (int r = 0; r < 4; ++r) {
            int grow = row0 + wm + mt * 16 + lq * 4 + r;
            if (grow >= M) continue;
            #pragma unroll
            for (int nt = 0; nt < 4; ++nt) {
                float v = acc[mt][nt][r] + bv[nt];
                if (relu) v = fmaxf(v, 0.f);
                Cb[(size_t)grow * N + col0 + wn + nt * 16 + lr] = __float2bfloat16(v);
            }
        }
    }

    // Fused attention-coefficient epilogue (gemm1 only).
    // Wave's 64 cols = exactly one head: pure in-wave reduce, no LDS.
    if (aS) {
        const int head = (col0 + wn) >> 6;
        float atS[4], atD[4];
        #pragma unroll
        for (int nt = 0; nt < 4; ++nt) {
            int c = col0 + wn + nt * 16 + lr;
            atS[nt] = attS[c];
            atD[nt] = attD[c];
        }
        #pragma unroll
        for (int mt = 0; mt < 2; ++mt) {
            #pragma unroll
            for (int r = 0; r < 4; ++r) {
                float vs = acc[mt][0][r] * atS[0] + acc[mt][1][r] * atS[1]
                         + acc[mt][2][r] * atS[2] + acc[mt][3][r] * atS[3];
                float vd = acc[mt][0][r] * atD[0] + acc[mt][1][r] * atD[1]
                         + acc[mt][2][r] * atD[2] + acc[mt][3][r] * atD[3];
                #pragma unroll
                for (int off = 1; off < 16; off <<= 1) {
                    vs += __shfl_xor(vs, off);
                    vd += __shfl_xor(vd, off);
                }
                if (lr == 0) {
                    int grow = row0 + wm + mt * 16 + lq * 4 + r;
                    if (grow < M) {
                        aS[grow * HEADS + head] = vs;
                        aD[grow * HEADS + head] = vd;
                    }
                }
            }
        }
    }
}

// ---------------------------------------------------------------------------
// gemm3 + ln2 fused (R7 geometry, FBM=32, 256 thr): fbuf-free.
// C = mid @ w2 + b2; val = C + hb; LN; write hb (final layer: split fp32).
// Block = 32 rows x 256 cols (full N), K=512, grid 625 (M=625*32 exact).
// R10 change (R7-class mechanism): A-staging deguarded + rebalanced —
// all 256 threads issue ONE 16B load (sr2=tid>>3 in [0,32), sc2=(tid&7)*8)
// instead of half the threads issuing two loads under `if (sr < FBM)`
// (exec-mask churn per K-chunk). Rows <= row0+31 <= 19999 < M: in-bounds.
// (FBM=64 R6 and 512-thr R8 variants both regressed — geometry frozen.)
// Row-LN: per-wave 16-lane shfl reduce -> 1KB LDS combine of 4 col-quarters.
// ---------------------------------------------------------------------------
#define FBM 32

__global__ __launch_bounds__(256) void gemm3_ln_kernel(
    const __hip_bfloat16* __restrict__ A,   // midb [M x FF_DIM]
    const __hip_bfloat16* __restrict__ BT,  // w2T  [C_DIM x FF_DIM]
    const float* __restrict__ bias,         // b2 [C_DIM]
    const float* __restrict__ ln_g, const float* __restrict__ ln_b,
    __hip_bfloat16* __restrict__ hb,        // residual in; LN out (non-final)
    float* __restrict__ out_split,          // final layer: split fp32 out
    int M)
{
    __shared__ short As[FBM * GLS];         // 4.5 KB
    __shared__ short Bs[C_DIM * GLS];       // 36 KB
    __shared__ float rsum[2][FBM][4];       // [s1|s2][row][col-quarter]

    const int tid = threadIdx.x;
    const int wave = tid >> 6, lane = tid & 63;
    const int lr = lane & 15, lq = lane >> 4;
    const int wn = wave * 64;               // column base for this wave
    const int row0 = blockIdx.x * FBM;

    const int sr = tid >> 2;                // 0..63   (B staging)
    const int sc = (tid & 3) * 16;
    const int sr2 = tid >> 3;               // 0..31   (A staging, all threads)
    const int sc2 = (tid & 7) * 8;          // shorts: 0..56

    f32x4 acc[2][4] = {};

    for (int k0 = 0; k0 < FF_DIM; k0 += GBK) {
        // A: 32 rows x 64 shorts; one unguarded 16B load per thread.
        i32x4 va = *(const i32x4*)&A[(size_t)(row0 + sr2) * FF_DIM + k0 + sc2];
        *(i32x4*)&As[sr2 * GLS + sc2] = va;
        #pragma unroll
        for (int rb = 0; rb < 4; ++rb) {
            const int br = rb * 64 + sr;
            const __hip_bfloat16* bp = &BT[(size_t)br * FF_DIM + k0 + sc];
            *(i32x4*)&Bs[br * GLS + sc] = *(const i32x4*)bp;
            *(i32x4*)&Bs[br * GLS + sc + 8] = *(const i32x4*)(bp + 8);
        }
        __syncthreads();

        #pragma unroll
        for (int ks = 0; ks < 2; ++ks) {
            bf16x8_t af[2], bfr[4];
            #pragma unroll
            for (int mt = 0; mt < 2; ++mt)
                af[mt] = *(const bf16x8_t*)&As[(mt * 16 + lr) * GLS + ks * 32 + lq * 8];
            #pragma unroll
            for (int nt = 0; nt < 4; ++nt)
                bfr[nt] = *(const bf16x8_t*)&Bs[(wn + nt * 16 + lr) * GLS + ks * 32 + lq * 8];
            #pragma unroll
            for (int mt = 0; mt < 2; ++mt)
                #pragma unroll
                for (int nt = 0; nt < 4; ++nt)
                    acc[mt][nt] = __builtin_amdgcn_mfma_f32_16x16x32_bf16(
                        af[mt], bfr[nt], acc[mt][nt], 0, 0, 0);
        }
        __syncthreads();
    }

    float bv[4];
    #pragma unroll
    for (int nt = 0; nt < 4; ++nt)
        bv[nt] = bias[wn + nt * 16 + lr];

    // val = C + b2 + residual; per-row partial sums over this wave's 64 cols
    const unsigned short* hbp = (const unsigned short*)hb;
    #pragma unroll
    for (int mt = 0; mt < 2; ++mt) {
        #pragma unroll
        for (int r = 0; r < 4; ++r) {
            const int rb = mt * 16 + lq * 4 + r;      // 0..31
            const int grow = row0 + rb;
            float s1 = 0.f, s2 = 0.f;
            #pragma unroll
            for (int nt = 0; nt < 4; ++nt) {
                float res = (grow < M)
                    ? bf2f(hbp[(size_t)grow * C_DIM + wn + nt * 16 + lr]) : 0.f;
                float v = acc[mt][nt][r] + bv[nt] + res;
                acc[mt][nt][r] = v;                   // keep for normalize phase
                s1 += v; s2 += v * v;
            }
            #pragma unroll
            for (int off = 1; off < 16; off <<= 1) {
                s1 += __shfl_xor(s1, off);
                s2 += __shfl_xor(s2, off);
            }
            if (lr == 0) {
                rsum[0][rb][wave] = s1;
                rsum[1][rb][wave] = s2;
            }
        }
    }
    __syncthreads();

    float g[4], bb[4];
    #pragma unroll
    for (int nt = 0; nt < 4; ++nt) {
        g[nt]  = ln_g[wn + nt * 16 + lr];
        bb[nt] = ln_b[wn + nt * 16 + lr];
    }

    #pragma unroll
    for (int mt = 0; mt < 2; ++mt) {
        #pragma unroll
        for (int r = 0; r < 4; ++r) {
            const int rb = mt * 16 + lq * 4 + r;
            const int grow = row0 + rb;
            if (grow >= M) continue;
            float s1 = (rsum[0][rb][0] + rsum[0][rb][1]) + (rsum[0][rb][2] + rsum[0][rb][3]);
            float s2 = (rsum[1][rb][0] + rsum[1][rb][1]) + (rsum[1][rb][2] + rsum[1][rb][3]);
            float mean = s1 * (1.0f / C_DIM);
            float inv = rsqrtf(s2 * (1.0f / C_DIM) - mean * mean + LN_EPS);
            if (out_split) {
                #pragma unroll
                for (int nt = 0; nt < 4; ++nt) {
                    float o = (acc[mt][nt][r] - mean) * inv * g[nt] + bb[nt];
                    int c = wn + nt * 16 + lr;
                    size_t off_ = (c < HID) ? ((size_t)grow * HID + c)
                                            : ((size_t)M * HID + (size_t)grow * HID + (c - HID));
                    out_split[off_] = o;
                }
            } else {
                #pragma unroll
                for (int nt = 0; nt < 4; ++nt) {
                    float o = (acc[mt][nt][r] - mean) * inv * g[nt] + bb[nt];
                    ((unsigned short*)hb)[(size_t)grow * C_DIM + wn + nt * 16 + lr] =
                        __bfloat16_as_ushort(__float2bfloat16(o));
                }
            }
        }
    }
}

// ---------------------------------------------------------------------------
// Fused GAT: per-edge exp weights in-loop + weighted bf16 gather + bias +
// residual (bf16 hb) + LN1. One WAVE per node; lane owns 8 channels (16B
// gathers); two 32-lane halves process disjoint edge halves; combined via
// shfl_xor(32). hb updated in place (bf16-only residual stream).
// ---------------------------------------------------------------------------
__global__ __launch_bounds__(256) void agg_kernel(
    const __hip_bfloat16* __restrict__ xhb, const float* __restrict__ a_s,
    const float* __restrict__ a_d, const int* __restrict__ csr,
    const int* __restrict__ offs, const float* __restrict__ gat_b,
    const float* __restrict__ ln_g, const float* __restrict__ ln_b,
    __hip_bfloat16* __restrict__ hb, int Nn)
{
    const int lane = threadIdx.x & 63;
    const int n = __builtin_amdgcn_readfirstlane(blockIdx.x * 4 + (threadIdx.x >> 6));
    if (n >= Nn) return;
    const int half = lane >> 5;
    const int sl = lane & 31;
    const int head = sl >> 3;            // 8 lanes per head
    const int c0 = sl * 8;               // 8 channels per lane
    const unsigned* x = (const unsigned*)xhb;   // packed bf16 pairs
    const size_t rowp = (size_t)n * (C_DIM / 2) + (c0 >> 1);

    const float ad = a_d[n * 4 + head];

    const int beg = offs[n], end = offs[n + 1];
    const int ne = end - beg;
    const int nh0 = (ne + 1) >> 1;
    int ih  = half ? (beg + nh0) : beg;
    int cnt = half ? (ne - nh0) : nh0;

    // residual from bf16 hb (issue early)
    i32x4 rv = *(const i32x4*)&((const unsigned*)hb)[rowp];

    float acc[8] = {};
    float z = 0.f;

    {
        float wself = __expf(leaky(a_s[n * 4 + head] + ad));
        if (half) {
            i32x4 xv = *(const i32x4*)&x[rowp];
            #pragma unroll
            for (int q = 0; q < 4; ++q) {
                float lo, hi; bf2x((unsigned)xv[q], lo, hi);
                acc[2 * q]     = wself * lo;
                acc[2 * q + 1] = wself * hi;
            }
            z = wself;
        }
    }

    for (; cnt >= 4; cnt -= 4, ih += 4) {
        int s0 = csr[ih], s1 = csr[ih + 1], s2 = csr[ih + 2], s3 = csr[ih + 3];
        float w0 = __expf(leaky(a_s[s0 * 4 + head] + ad));
        float w1 = __expf(leaky(a_s[s1 * 4 + head] + ad));
        float w2 = __expf(leaky(a_s[s2 * 4 + head] + ad));
        float w3 = __expf(leaky(a_s[s3 * 4 + head] + ad));
        i32x4 x0 = *(const i32x4*)&x[(size_t)s0 * (C_DIM / 2) + (c0 >> 1)];
        i32x4 x1 = *(const i32x4*)&x[(size_t)s1 * (C_DIM / 2) + (c0 >> 1)];
        i32x4 x2 = *(const i32x4*)&x[(size_t)s2 * (C_DIM / 2) + (c0 >> 1)];
        i32x4 x3 = *(const i32x4*)&x[(size_t)s3 * (C_DIM / 2) + (c0 >> 1)];
        #pragma unroll
        for (int q = 0; q < 4; ++q) {
            float lo, hi;
            bf2x((unsigned)x0[q], lo, hi);
            acc[2 * q] += w0 * lo; acc[2 * q + 1] += w0 * hi;
            bf2x((unsigned)x1[q], lo, hi);
            acc[2 * q] += w1 * lo; acc[2 * q + 1] += w1 * hi;
            bf2x((unsigned)x2[q], lo, hi);
            acc[2 * q] += w2 * lo; acc[2 * q + 1] += w2 * hi;
            bf2x((unsigned)x3[q], lo, hi);
            acc[2 * q] += w3 * lo; acc[2 * q + 1] += w3 * hi;
        }
        z += (w0 + w1) + (w2 + w3);
    }
    for (; cnt > 0; --cnt, ++ih) {
        int s0 = csr[ih];
        float w0 = __expf(leaky(a_s[s0 * 4 + head] + ad));
        i32x4 x0 = *(const i32x4*)&x[(size_t)s0 * (C_DIM / 2) + (c0 >> 1)];
        #pragma unroll
        for (int q = 0; q < 4; ++q) {
            float lo, hi; bf2x((unsigned)x0[q], lo, hi);
            acc[2 * q] += w0 * lo; acc[2 * q + 1] += w0 * hi;
        }
        z += w0;
    }

    #pragma unroll
    for (int j = 0; j < 8; ++j) acc[j] += __shfl_xor(acc[j], 32);
    z += __shfl_xor(z, 32);

    float res[8];
    #pragma unroll
    for (int q = 0; q < 4; ++q) bf2x((unsigned)rv[q], res[2 * q], res[2 * q + 1]);

    float4 gb0 = *(const float4*)&gat_b[c0];
    float4 gb1 = *(const float4*)&gat_b[c0 + 4];
    float gb[8] = {gb0.x, gb0.y, gb0.z, gb0.w, gb1.x, gb1.y, gb1.z, gb1.w};
    float rz = 1.0f / z;
    float val[8];
    #pragma unroll
    for (int j = 0; j < 8; ++j) val[j] = acc[j] * rz + gb[j] + res[j];

    // LN: each channel appears on 2 lanes -> normalize by 512.
    float s1 = 0.f, s2 = 0.f;
    #pragma unroll
    for (int j = 0; j < 8; ++j) { s1 += val[j]; s2 += val[j] * val[j]; }
    #pragma unroll
    for (int off = 1; off < 64; off <<= 1) {
        s1 += __shfl_xor(s1, off);
        s2 += __shfl_xor(s2, off);
    }
    float mean = s1 * (1.0f / (2 * C_DIM));
    float inv = rsqrtf(s2 * (1.0f / (2 * C_DIM)) - mean * mean + LN_EPS);

    if (half == 0) {
        float4 g0 = *(const float4*)&ln_g[c0];
        float4 g1 = *(const float4*)&ln_g[c0 + 4];
        float4 bb0 = *(const float4*)&ln_b[c0];
        float4 bb1 = *(const float4*)&ln_b[c0 + 4];
        float g[8] = {g0.x, g0.y, g0.z, g0.w, g1.x, g1.y, g1.z, g1.w};
        float bb[8] = {bb0.x, bb0.y, bb0.z, bb0.w, bb1.x, bb1.y, bb1.z, bb1.w};
        float o[8];
        #pragma unroll
        for (int j = 0; j < 8; ++j) o[j] = (val[j] - mean) * inv * g[j] + bb[j];
        i32x4 ob;
        ob[0] = (int)packbf(o[0], o[1]);
        ob[1] = (int)packbf(o[2], o[3]);
        ob[2] = (int)packbf(o[4], o[5]);
        ob[3] = (int)packbf(o[6], o[7]);
        *(i32x4*)&((unsigned*)hb)[rowp] = ob;
    }
}

// ---------------------------------------------------------------------------
// Host launch
// ---------------------------------------------------------------------------
extern "C" void kernel_launch(void* const* d_in, const int* in_sizes, int n_in,
                              void* d_out, int out_size, void* d_ws, size_t ws_size,
                              hipStream_t stream)
{
    const float* hf       = (const float*)d_in[0];
    const float* hs       = (const float*)d_in[1];
    const int*   edge     = (const int*)  d_in[2];
    const float* W        = (const float*)d_in[3];
    const float* att_src  = (const float*)d_in[4];
    const float* att_dst  = (const float*)d_in[5];
    const float* gat_b    = (const float*)d_in[6];
    const float* w1       = (const float*)d_in[7];
    const float* b1       = (const float*)d_in[8];
    const float* w2       = (const float*)d_in[9];
    const float* b2       = (const float*)d_in[10];
    const float* ln1g     = (const float*)d_in[11];
    const float* ln1b     = (const float*)d_in[12];
    const float* ln2g     = (const float*)d_in[13];
    const float* ln2b     = (const float*)d_in[14];
    float* out = (float*)d_out;

    const int N = in_sizes[0] / HID;       // 20000
    const int E = in_sizes[2] / 2;         // 320000
    const int* e_src = edge;
    const int* e_dst = edge + E;

    char* p = (char*)d_ws;
    auto alloc = [&](size_t bytes) {
        char* r = p;
        p += (bytes + 255) & ~(size_t)255;
        return (void*)r;
    };
    const int NPAD = N + 64;               // pad: unguarded GEMM A-staging reads past M
    __hip_bfloat16* hb     = (__hip_bfloat16*)alloc((size_t)NPAD * C_DIM * 2);
    __hip_bfloat16* xhb    = (__hip_bfloat16*)alloc((size_t)N * C_DIM * 2);  // gemm1 out
    __hip_bfloat16* midb   = (__hip_bfloat16*)alloc((size_t)N * FF_DIM * 2);
    float*          a_s    = (float*)alloc((size_t)N * HEADS * 4);
    float*          a_d    = (float*)alloc((size_t)N * HEADS * 4);
    int*            counts = (int*)alloc((size_t)N * 4);
    int*            offs   = (int*)alloc((size_t)(N + 1) * 4);
    int*            cursor = (int*)alloc((size_t)N * 4);
    int*            csr    = (int*)alloc((size_t)E * 4);
    __hip_bfloat16* WT     = (__hip_bfloat16*)alloc((size_t)NLAYERS * C_DIM * C_DIM * 2);
    __hip_bfloat16* w1T    = (__hip_bfloat16*)alloc((size_t)NLAYERS * C_DIM * FF_DIM * 2);
    __hip_bfloat16* w2T    = (__hip_bfloat16*)alloc((size_t)NLAYERS * FF_DIM * C_DIM * 2);

    {
        int total = N * C_DIM;
        concat_kernel<<<(total + 255) / 256, 256, 0, stream>>>(hf, hs, hb, N);
    }
    transp_bf16_kernel<<<dim3(C_DIM / 32, C_DIM / 32, NLAYERS), 256, 0, stream>>>(W, WT, C_DIM, C_DIM);
    transp_bf16_kernel<<<dim3(FF_DIM / 32, C_DIM / 32, NLAYERS), 256, 0, stream>>>(w1, w1T, C_DIM, FF_DIM);
    transp_bf16_kernel<<<dim3(C_DIM / 32, FF_DIM / 32, NLAYERS), 256, 0, stream>>>(w2, w2T, FF_DIM, C_DIM);

    zero_i32_kernel<<<(N + 255) / 256, 256, 0, stream>>>(counts, N);
    hist_kernel<<<(E + 255) / 256, 256, 0, stream>>>(e_dst, counts, E);
    scan_kernel<<<1, 1024, 0, stream>>>(counts, offs, cursor, N);
    fill_kernel<<<(E + 255) / 256, 256, 0, stream>>>(e_src, e_dst, cursor, csr, E);

    const int gm = (N + GBM - 1) / GBM;   // 313
    const int gf = (N + FBM - 1) / FBM;   // 625

    for (int l = 0; l < NLAYERS; ++l) {
        const __hip_bfloat16* Wl  = WT  + (size_t)l * C_DIM * C_DIM;
        const __hip_bfloat16* w1l = w1T + (size_t)l * C_DIM * FF_DIM;
        const __hip_bfloat16* w2l = w2T + (size_t)l * FF_DIM * C_DIM;
        const float* asl  = att_src + (size_t)l * C_DIM;
        const float* adl  = att_dst + (size_t)l * C_DIM;
        const float* gbl  = gat_b + (size_t)l * C_DIM;
        const float* b1l  = b1 + (size_t)l * FF_DIM;
        const float* b2l  = b2 + (size_t)l * C_DIM;
        const float* g1l  = ln1g + (size_t)l * C_DIM;
        const float* be1l = ln1b + (size_t)l * C_DIM;
        const float* g2l  = ln2g + (size_t)l * C_DIM;
        const float* be2l = ln2b + (size_t)l * C_DIM;

        // xhb = hb @ W[l] (bf16 out) + fused a_s/a_d epilogue
        gemm_bf16_kernel<<<dim3(gm, C_DIM / GBN), 256, 0, stream>>>(
            hb, Wl, nullptr, xhb, asl, adl, a_s, a_d, N, C_DIM, C_DIM, 0);
        // fused exp-weights + softmax-agg + bias + residual + LN1 (hb in place)
        agg_kernel<<<(N + 3) / 4, 256, 0, stream>>>(
            xhb, a_s, a_d, csr, offs, gbl, g1l, be1l, hb, N);
        // mid = relu(hb @ w1 + b1)  (bf16 out)
        gemm_bf16_kernel<<<dim3(gm, FF_DIM / GBN), 256, 0, stream>>>(
            hb, w1l, b1l, midb, nullptr, nullptr, nullptr, nullptr,
            N, FF_DIM, C_DIM, 1);
        // hb = LN(mid @ w2 + b2 + hb)  [fused gemm3+ln2; final layer -> out]
        gemm3_ln_kernel<<<gf, 256, 0, stream>>>(
            midb, w2l, b2l, g2l, be2l, hb,
            (l == NLAYERS - 1) ? out : nullptr, N);
    }
}

// Round 11
// 1142.831 us; speedup vs baseline: 1.0261x; 1.0039x over previous
//
#include <hip/hip_runtime.h>
#include <hip/hip_bf16.h>
#include <math.h>

// Problem dims (fixed by reference)
#define C_DIM 256      // h width
#define HID 128
#define HEADS 4
#define OC 64          // per-head out channels
#define FF_DIM 512
#define NLAYERS 12

constexpr float LN_EPS = 1e-5f;
constexpr float SLOPE  = 0.2f;

typedef __attribute__((ext_vector_type(4))) float f32x4;
typedef __attribute__((ext_vector_type(8))) short bf16x8_t;
typedef __attribute__((ext_vector_type(4))) int i32x4;

__device__ __forceinline__ float leaky(float x) { return x > 0.f ? x : SLOPE * x; }

__device__ __forceinline__ float bf2f(unsigned short u) {
    union { unsigned i; float f; } v; v.i = ((unsigned)u) << 16; return v.f;
}
__device__ __forceinline__ void bf2x(unsigned u, float& lo, float& hi) {
    union { unsigned i; float f; } a, b;
    a.i = u << 16; b.i = u & 0xffff0000u;
    lo = a.f; hi = b.f;
}
__device__ __forceinline__ unsigned packbf(float lo, float hi) {
    unsigned a = __bfloat16_as_ushort(__float2bfloat16(lo));
    unsigned b = __bfloat16_as_ushort(__float2bfloat16(hi));
    return a | (b << 16);
}

// ---------------------------------------------------------------------------
// Small utility kernels
// ---------------------------------------------------------------------------
__global__ void zero_i32_kernel(int* __restrict__ p, int n) {
    int i = blockIdx.x * blockDim.x + threadIdx.x;
    if (i < n) p[i] = 0;
}

// bf16-only residual stream: concat writes hb only
__global__ void concat_kernel(const float* __restrict__ hf, const float* __restrict__ hs,
                              __hip_bfloat16* __restrict__ hb, int Nn) {
    int idx = blockIdx.x * blockDim.x + threadIdx.x;
    int total = Nn * C_DIM;
    if (idx < total) {
        int n = idx >> 8;
        int c = idx & 255;
        float v = (c < HID) ? hf[n * HID + c] : hs[n * HID + (c - HID)];
        hb[idx] = __float2bfloat16(v);
    }
}

// Transpose + convert weights: in [L][K][N] fp32 -> out [L][N][K] bf16
__global__ void transp_bf16_kernel(const float* __restrict__ in,
                                   __hip_bfloat16* __restrict__ out, int K, int N) {
    __shared__ float t[32][33];
    const float* inl = in + (size_t)blockIdx.z * K * N;
    __hip_bfloat16* outl = out + (size_t)blockIdx.z * K * N;
    int kb = blockIdx.y * 32, nb = blockIdx.x * 32;
    int tx = threadIdx.x & 31, ty = threadIdx.x >> 5; // 32x8
    #pragma unroll
    for (int r = 0; r < 32; r += 8)
        t[ty + r][tx] = inl[(size_t)(kb + ty + r) * N + nb + tx];
    __syncthreads();
    #pragma unroll
    for (int r = 0; r < 32; r += 8)
        outl[(size_t)(nb + ty + r) * K + kb + tx] = __float2bfloat16(t[tx][ty + r]);
}

// ---------------------------------------------------------------------------
// CSR build: histogram of dst, exclusive scan (wave-shuffle), fill src lists
// ---------------------------------------------------------------------------
__global__ void hist_kernel(const int* __restrict__ dst, int* __restrict__ counts, int E) {
    int e = blockIdx.x * blockDim.x + threadIdx.x;
    if (e < E) atomicAdd(&counts[dst[e]], 1);
}

// single block, 1024 threads = 16 waves. Wave shuffle scan + serial wave-sum scan.
__global__ void scan_kernel(const int* __restrict__ counts, int* __restrict__ offsets,
                            int* __restrict__ cursor, int n) {
    __shared__ int wsum[16];
    __shared__ int carry_s;
    const int lane = threadIdx.x & 63, wid = threadIdx.x >> 6;
    if (threadIdx.x == 0) carry_s = 0;
    __syncthreads();
    for (int base = 0; base < n; base += 1024) {
        int i = base + (int)threadIdx.x;
        int v = (i < n) ? counts[i] : 0;
        int x = v;
        #pragma unroll
        for (int off = 1; off < 64; off <<= 1) {
            int t = __shfl_up(x, off);
            if (lane >= off) x += t;
        }
        if (lane == 63) wsum[wid] = x;
        __syncthreads();
        if (threadIdx.x == 0) {
            int acc = carry_s;
            #pragma unroll
            for (int w = 0; w < 16; ++w) { int t = wsum[w]; wsum[w] = acc; acc += t; }
            carry_s = acc;
        }
        __syncthreads();
        int excl = wsum[wid] + x - v;
        if (i < n) { offsets[i] = excl; cursor[i] = excl; }
        __syncthreads();
    }
    if (threadIdx.x == 0) offsets[n] = carry_s;
}

__global__ void fill_kernel(const int* __restrict__ src, const int* __restrict__ dst,
                            int* __restrict__ cursor, int* __restrict__ csr_src, int E) {
    int e = blockIdx.x * blockDim.x + threadIdx.x;
    if (e < E) {
        int d = dst[e];
        int p = atomicAdd(&cursor[d], 1);
        csr_src[p] = src[e];
    }
}

// ---------------------------------------------------------------------------
// bf16 MFMA GEMM (R7-verified BEST state, 1134.7us): 64x128 tile, BK=64,
// 256 thr = 4 waves (2m x 2n), each wave 32 rows x 64 cols (acc 2x4).
// Register staging -> LDS (GLS=72 pad, 2-way alias free). A-staging
// UNGUARDED: A buffers padded +64 rows. Runtime K loop.
// Sharp local optimum — regressed variants: 128^2 gl_lds (R0 1297),
// 2-phase dbuf (R3 1357), FBM=64 (R6 1261), 512-thr (R8 1173),
// K-unroll (R9 1164), staging rebalance (R10 1147).
// gemm1 attention epilogue: wave's 64 cols = exactly one head -> pure
// in-wave 16-lane reduce, no LDS combine, no extra barrier.
// C/D: col=lane&15, row=(lane>>4)*4+reg  [verified m89/m91]
// ---------------------------------------------------------------------------
#define GBM 64
#define GBN 128
#define GBK 64
#define GLS 72   // LDS row stride (shorts): 144B; 2-way bank alias = free

__global__ __launch_bounds__(256) void gemm_bf16_kernel(
    const __hip_bfloat16* __restrict__ A,   // [M x K] bf16 row-major (rows padded +64)
    const __hip_bfloat16* __restrict__ BT,  // [N x K] bf16 row-major (B^T)
    const float* __restrict__ bias,         // [N] or null
    __hip_bfloat16* __restrict__ Cb,        // bf16 out
    const float* __restrict__ attS,         // [N] att_src slice or null
    const float* __restrict__ attD,
    float* __restrict__ aS,                 // [M x HEADS] out or null
    float* __restrict__ aD,
    int M, int N, int K, int relu)
{
    __shared__ short As[GBM * GLS];          // 9.2 KB
    __shared__ short Bs[GBN * GLS];          // 18.4 KB
    const int tid = threadIdx.x;
    const int wave = tid >> 6, lane = tid & 63;
    const int lr = lane & 15, lq = lane >> 4;
    const int wm = (wave >> 1) * 32, wn = (wave & 1) * 64;
    const int row0 = blockIdx.x * GBM, col0 = blockIdx.y * GBN;

    const int sra = tid >> 2;             // A staging row 0..63
    const int sca = (tid & 3) * 16;       // shorts: 0,16,32,48
    const int srb = tid >> 1;             // B staging row 0..127
    const int scb = (tid & 1) * 32;       // shorts: 0,32

    f32x4 acc[2][4] = {};

    for (int k0 = 0; k0 < K; k0 += GBK) {
        const __hip_bfloat16* ap = &A[(size_t)(row0 + sra) * K + k0 + sca];
        i32x4 va0 = *(const i32x4*)ap;
        i32x4 va1 = *(const i32x4*)(ap + 8);
        const __hip_bfloat16* bp = &BT[(size_t)(col0 + srb) * K + k0 + scb];
        i32x4 vb0 = *(const i32x4*)bp;
        i32x4 vb1 = *(const i32x4*)(bp + 8);
        i32x4 vb2 = *(const i32x4*)(bp + 16);
        i32x4 vb3 = *(const i32x4*)(bp + 24);
        *(i32x4*)&As[sra * GLS + sca] = va0;
        *(i32x4*)&As[sra * GLS + sca + 8] = va1;
        *(i32x4*)&Bs[srb * GLS + scb] = vb0;
        *(i32x4*)&Bs[srb * GLS + scb + 8] = vb1;
        *(i32x4*)&Bs[srb * GLS + scb + 16] = vb2;
        *(i32x4*)&Bs[srb * GLS + scb + 24] = vb3;
        __syncthreads();

        #pragma unroll
        for (int ks = 0; ks < 2; ++ks) {
            bf16x8_t af[2], bfr[4];
            #pragma unroll
            for (int t = 0; t < 2; ++t)
                af[t]  = *(const bf16x8_t*)&As[(wm + t * 16 + lr) * GLS + ks * 32 + lq * 8];
            #pragma unroll
            for (int t = 0; t < 4; ++t)
                bfr[t] = *(const bf16x8_t*)&Bs[(wn + t * 16 + lr) * GLS + ks * 32 + lq * 8];
            #pragma unroll
            for (int mt = 0; mt < 2; ++mt)
                #pragma unroll
                for (int nt = 0; nt < 4; ++nt)
                    acc[mt][nt] = __builtin_amdgcn_mfma_f32_16x16x32_bf16(
                        af[mt], bfr[nt], acc[mt][nt], 0, 0, 0);
        }
        __syncthreads();
    }

    float bv[4];
    #pragma unroll
    for (int nt = 0; nt < 4; ++nt)
        bv[nt] = bias ? bias[col0 + wn + nt * 16 + lr] : 0.f;

    #pragma unroll
    for (int mt = 0; mt < 2; ++mt) {
        #pragma unroll
        for (int r = 0; r < 4; ++r) {
            int grow = row0 + wm + mt * 16 + lq * 4 + r;
            if (grow >= M) continue;
            #pragma unroll
            for (int nt = 0; nt < 4; ++nt) {
                float v = acc[mt][nt][r] + bv[nt];
                if (relu) v = fmaxf(v, 0.f);
                Cb[(size_t)grow * N + col0 + wn + nt * 16 + lr] = __float2bfloat16(v);
            }
        }
    }

    // Fused attention-coefficient epilogue (gemm1 only).
    // Wave's 64 cols = exactly one head: pure in-wave reduce, no LDS.
    if (aS) {
        const int head = (col0 + wn) >> 6;
        float atS[4], atD[4];
        #pragma unroll
        for (int nt = 0; nt < 4; ++nt) {
            int c = col0 + wn + nt * 16 + lr;
            atS[nt] = attS[c];
            atD[nt] = attD[c];
        }
        #pragma unroll
        for (int mt = 0; mt < 2; ++mt) {
            #pragma unroll
            for (int r = 0; r < 4; ++r) {
                float vs = acc[mt][0][r] * atS[0] + acc[mt][1][r] * atS[1]
                         + acc[mt][2][r] * atS[2] + acc[mt][3][r] * atS[3];
                float vd = acc[mt][0][r] * atD[0] + acc[mt][1][r] * atD[1]
                         + acc[mt][2][r] * atD[2] + acc[mt][3][r] * atD[3];
                #pragma unroll
                for (int off = 1; off < 16; off <<= 1) {
                    vs += __shfl_xor(vs, off);
                    vd += __shfl_xor(vd, off);
                }
                if (lr == 0) {
                    int grow = row0 + wm + mt * 16 + lq * 4 + r;
                    if (grow < M) {
                        aS[grow * HEADS + head] = vs;
                        aD[grow * HEADS + head] = vd;
                    }
                }
            }
        }
    }
}

// ---------------------------------------------------------------------------
// gemm3 + ln2 fused (R7-verified, FBM=32, 256 thr): fbuf-free.
// C = mid @ w2 + b2; val = C + hb; LN; write hb (final layer: split fp32).
// Block = 32 rows x 256 cols (full N), K=512, grid 625 (M=625*32 exact).
// 4 waves split columns; acc 2x4 = 32 VGPRs. Regressed variants: FBM=64
// (R6), 512-thr (R8), deguarded A-staging rebalance (R10).
// Row-LN: per-wave 16-lane shfl reduce -> 1KB LDS combine of 4 col-quarters.
// ---------------------------------------------------------------------------
#define FBM 32

__global__ __launch_bounds__(256) void gemm3_ln_kernel(
    const __hip_bfloat16* __restrict__ A,   // midb [M x FF_DIM]
    const __hip_bfloat16* __restrict__ BT,  // w2T  [C_DIM x FF_DIM]
    const float* __restrict__ bias,         // b2 [C_DIM]
    const float* __restrict__ ln_g, const float* __restrict__ ln_b,
    __hip_bfloat16* __restrict__ hb,        // residual in; LN out (non-final)
    float* __restrict__ out_split,          // final layer: split fp32 out
    int M)
{
    __shared__ short As[FBM * GLS];         // 4.5 KB
    __shared__ short Bs[C_DIM * GLS];       // 36 KB
    __shared__ float rsum[2][FBM][4];       // [s1|s2][row][col-quarter]

    const int tid = threadIdx.x;
    const int wave = tid >> 6, lane = tid & 63;
    const int lr = lane & 15, lq = lane >> 4;
    const int wn = wave * 64;               // column base for this wave
    const int row0 = blockIdx.x * FBM;

    const int sr = tid >> 2;                // 0..63
    const int sc = (tid & 3) * 16;

    f32x4 acc[2][4] = {};

    for (int k0 = 0; k0 < FF_DIM; k0 += GBK) {
        if (sr < FBM) {
            const __hip_bfloat16* ap = &A[(size_t)(row0 + sr) * FF_DIM + k0 + sc];
            *(i32x4*)&As[sr * GLS + sc] = *(const i32x4*)ap;
            *(i32x4*)&As[sr * GLS + sc + 8] = *(const i32x4*)(ap + 8);
        }
        #pragma unroll
        for (int rb = 0; rb < 4; ++rb) {
            const int br = rb * 64 + sr;
            const __hip_bfloat16* bp = &BT[(size_t)br * FF_DIM + k0 + sc];
            *(i32x4*)&Bs[br * GLS + sc] = *(const i32x4*)bp;
            *(i32x4*)&Bs[br * GLS + sc + 8] = *(const i32x4*)(bp + 8);
        }
        __syncthreads();

        #pragma unroll
        for (int ks = 0; ks < 2; ++ks) {
            bf16x8_t af[2], bfr[4];
            #pragma unroll
            for (int mt = 0; mt < 2; ++mt)
                af[mt] = *(const bf16x8_t*)&As[(mt * 16 + lr) * GLS + ks * 32 + lq * 8];
            #pragma unroll
            for (int nt = 0; nt < 4; ++nt)
                bfr[nt] = *(const bf16x8_t*)&Bs[(wn + nt * 16 + lr) * GLS + ks * 32 + lq * 8];
            #pragma unroll
            for (int mt = 0; mt < 2; ++mt)
                #pragma unroll
                for (int nt = 0; nt < 4; ++nt)
                    acc[mt][nt] = __builtin_amdgcn_mfma_f32_16x16x32_bf16(
                        af[mt], bfr[nt], acc[mt][nt], 0, 0, 0);
        }
        __syncthreads();
    }

    float bv[4];
    #pragma unroll
    for (int nt = 0; nt < 4; ++nt)
        bv[nt] = bias[wn + nt * 16 + lr];

    // val = C + b2 + residual; per-row partial sums over this wave's 64 cols
    const unsigned short* hbp = (const unsigned short*)hb;
    #pragma unroll
    for (int mt = 0; mt < 2; ++mt) {
        #pragma unroll
        for (int r = 0; r < 4; ++r) {
            const int rb = mt * 16 + lq * 4 + r;      // 0..31
            const int grow = row0 + rb;
            float s1 = 0.f, s2 = 0.f;
            #pragma unroll
            for (int nt = 0; nt < 4; ++nt) {
                float res = (grow < M)
                    ? bf2f(hbp[(size_t)grow * C_DIM + wn + nt * 16 + lr]) : 0.f;
                float v = acc[mt][nt][r] + bv[nt] + res;
                acc[mt][nt][r] = v;                   // keep for normalize phase
                s1 += v; s2 += v * v;
            }
            #pragma unroll
            for (int off = 1; off < 16; off <<= 1) {
                s1 += __shfl_xor(s1, off);
                s2 += __shfl_xor(s2, off);
            }
            if (lr == 0) {
                rsum[0][rb][wave] = s1;
                rsum[1][rb][wave] = s2;
            }
        }
    }
    __syncthreads();

    float g[4], bb[4];
    #pragma unroll
    for (int nt = 0; nt < 4; ++nt) {
        g[nt]  = ln_g[wn + nt * 16 + lr];
        bb[nt] = ln_b[wn + nt * 16 + lr];
    }

    #pragma unroll
    for (int mt = 0; mt < 2; ++mt) {
        #pragma unroll
        for (int r = 0; r < 4; ++r) {
            const int rb = mt * 16 + lq * 4 + r;
            const int grow = row0 + rb;
            if (grow >= M) continue;
            float s1 = (rsum[0][rb][0] + rsum[0][rb][1]) + (rsum[0][rb][2] + rsum[0][rb][3]);
            float s2 = (rsum[1][rb][0] + rsum[1][rb][1]) + (rsum[1][rb][2] + rsum[1][rb][3]);
            float mean = s1 * (1.0f / C_DIM);
            float inv = rsqrtf(s2 * (1.0f / C_DIM) - mean * mean + LN_EPS);
            if (out_split) {
                #pragma unroll
                for (int nt = 0; nt < 4; ++nt) {
                    float o = (acc[mt][nt][r] - mean) * inv * g[nt] + bb[nt];
                    int c = wn + nt * 16 + lr;
                    size_t off_ = (c < HID) ? ((size_t)grow * HID + c)
                                            : ((size_t)M * HID + (size_t)grow * HID + (c - HID));
                    out_split[off_] = o;
                }
            } else {
                #pragma unroll
                for (int nt = 0; nt < 4; ++nt) {
                    float o = (acc[mt][nt][r] - mean) * inv * g[nt] + bb[nt];
                    ((unsigned short*)hb)[(size_t)grow * C_DIM + wn + nt * 16 + lr] =
                        __bfloat16_as_ushort(__float2bfloat16(o));
                }
            }
        }
    }
}

// ---------------------------------------------------------------------------
// Fused GAT: per-edge exp weights in-loop + weighted bf16 gather + bias +
// residual (bf16 hb) + LN1. One WAVE per node; lane owns 8 channels (16B
// gathers); two 32-lane halves process disjoint edge halves; combined via
// shfl_xor(32). hb updated in place (bf16-only residual stream).
// ---------------------------------------------------------------------------
__global__ __launch_bounds__(256) void agg_kernel(
    const __hip_bfloat16* __restrict__ xhb, const float* __restrict__ a_s,
    const float* __restrict__ a_d, const int* __restrict__ csr,
    const int* __restrict__ offs, const float* __restrict__ gat_b,
    const float* __restrict__ ln_g, const float* __restrict__ ln_b,
    __hip_bfloat16* __restrict__ hb, int Nn)
{
    const int lane = threadIdx.x & 63;
    const int n = __builtin_amdgcn_readfirstlane(blockIdx.x * 4 + (threadIdx.x >> 6));
    if (n >= Nn) return;
    const int half = lane >> 5;
    const int sl = lane & 31;
    const int head = sl >> 3;            // 8 lanes per head
    const int c0 = sl * 8;               // 8 channels per lane
    const unsigned* x = (const unsigned*)xhb;   // packed bf16 pairs
    const size_t rowp = (size_t)n * (C_DIM / 2) + (c0 >> 1);

    const float ad = a_d[n * 4 + head];

    const int beg = offs[n], end = offs[n + 1];
    const int ne = end - beg;
    const int nh0 = (ne + 1) >> 1;
    int ih  = half ? (beg + nh0) : beg;
    int cnt = half ? (ne - nh0) : nh0;

    // residual from bf16 hb (issue early)
    i32x4 rv = *(const i32x4*)&((const unsigned*)hb)[rowp];

    float acc[8] = {};
    float z = 0.f;

    {
        float wself = __expf(leaky(a_s[n * 4 + head] + ad));
        if (half) {
            i32x4 xv = *(const i32x4*)&x[rowp];
            #pragma unroll
            for (int q = 0; q < 4; ++q) {
                float lo, hi; bf2x((unsigned)xv[q], lo, hi);
                acc[2 * q]     = wself * lo;
                acc[2 * q + 1] = wself * hi;
            }
            z = wself;
        }
    }

    for (; cnt >= 4; cnt -= 4, ih += 4) {
        int s0 = csr[ih], s1 = csr[ih + 1], s2 = csr[ih + 2], s3 = csr[ih + 3];
        float w0 = __expf(leaky(a_s[s0 * 4 + head] + ad));
        float w1 = __expf(leaky(a_s[s1 * 4 + head] + ad));
        float w2 = __expf(leaky(a_s[s2 * 4 + head] + ad));
        float w3 = __expf(leaky(a_s[s3 * 4 + head] + ad));
        i32x4 x0 = *(const i32x4*)&x[(size_t)s0 * (C_DIM / 2) + (c0 >> 1)];
        i32x4 x1 = *(const i32x4*)&x[(size_t)s1 * (C_DIM / 2) + (c0 >> 1)];
        i32x4 x2 = *(const i32x4*)&x[(size_t)s2 * (C_DIM / 2) + (c0 >> 1)];
        i32x4 x3 = *(const i32x4*)&x[(size_t)s3 * (C_DIM / 2) + (c0 >> 1)];
        #pragma unroll
        for (int q = 0; q < 4; ++q) {
            float lo, hi;
            bf2x((unsigned)x0[q], lo, hi);
            acc[2 * q] += w0 * lo; acc[2 * q + 1] += w0 * hi;
            bf2x((unsigned)x1[q], lo, hi);
            acc[2 * q] += w1 * lo; acc[2 * q + 1] += w1 * hi;
            bf2x((unsigned)x2[q], lo, hi);
            acc[2 * q] += w2 * lo; acc[2 * q + 1] += w2 * hi;
            bf2x((unsigned)x3[q], lo, hi);
            acc[2 * q] += w3 * lo; acc[2 * q + 1] += w3 * hi;
        }
        z += (w0 + w1) + (w2 + w3);
    }
    for (; cnt > 0; --cnt, ++ih) {
        int s0 = csr[ih];
        float w0 = __expf(leaky(a_s[s0 * 4 + head] + ad));
        i32x4 x0 = *(const i32x4*)&x[(size_t)s0 * (C_DIM / 2) + (c0 >> 1)];
        #pragma unroll
        for (int q = 0; q < 4; ++q) {
            float lo, hi; bf2x((unsigned)x0[q], lo, hi);
            acc[2 * q] += w0 * lo; acc[2 * q + 1] += w0 * hi;
        }
        z += w0;
    }

    #pragma unroll
    for (int j = 0; j < 8; ++j) acc[j] += __shfl_xor(acc[j], 32);
    z += __shfl_xor(z, 32);

    float res[8];
    #pragma unroll
    for (int q = 0; q < 4; ++q) bf2x((unsigned)rv[q], res[2 * q], res[2 * q + 1]);

    float4 gb0 = *(const float4*)&gat_b[c0];
    float4 gb1 = *(const float4*)&gat_b[c0 + 4];
    float gb[8] = {gb0.x, gb0.y, gb0.z, gb0.w, gb1.x, gb1.y, gb1.z, gb1.w};
    float rz = 1.0f / z;
    float val[8];
    #pragma unroll
    for (int j = 0; j < 8; ++j) val[j] = acc[j] * rz + gb[j] + res[j];

    // LN: each channel appears on 2 lanes -> normalize by 512.
    float s1 = 0.f, s2 = 0.f;
    #pragma unroll
    for (int j = 0; j < 8; ++j) { s1 += val[j]; s2 += val[j] * val[j]; }
    #pragma unroll
    for (int off = 1; off < 64; off <<= 1) {
        s1 += __shfl_xor(s1, off);
        s2 += __shfl_xor(s2, off);
    }
    float mean = s1 * (1.0f / (2 * C_DIM));
    float inv = rsqrtf(s2 * (1.0f / (2 * C_DIM)) - mean * mean + LN_EPS);

    if (half == 0) {
        float4 g0 = *(const float4*)&ln_g[c0];
        float4 g1 = *(const float4*)&ln_g[c0 + 4];
        float4 bb0 = *(const float4*)&ln_b[c0];
        float4 bb1 = *(const float4*)&ln_b[c0 + 4];
        float g[8] = {g0.x, g0.y, g0.z, g0.w, g1.x, g1.y, g1.z, g1.w};
        float bb[8] = {bb0.x, bb0.y, bb0.z, bb0.w, bb1.x, bb1.y, bb1.z, bb1.w};
        float o[8];
        #pragma unroll
        for (int j = 0; j < 8; ++j) o[j] = (val[j] - mean) * inv * g[j] + bb[j];
        i32x4 ob;
        ob[0] = (int)packbf(o[0], o[1]);
        ob[1] = (int)packbf(o[2], o[3]);
        ob[2] = (int)packbf(o[4], o[5]);
        ob[3] = (int)packbf(o[6], o[7]);
        *(i32x4*)&((unsigned*)hb)[rowp] = ob;
    }
}

// ---------------------------------------------------------------------------
// Host launch
// ---------------------------------------------------------------------------
extern "C" void kernel_launch(void* const* d_in, const int* in_sizes, int n_in,
                              void* d_out, int out_size, void* d_ws, size_t ws_size,
                              hipStream_t stream)
{
    const float* hf       = (const float*)d_in[0];
    const float* hs       = (const float*)d_in[1];
    const int*   edge     = (const int*)  d_in[2];
    const float* W        = (const float*)d_in[3];
    const float* att_src  = (const float*)d_in[4];
    const float* att_dst  = (const float*)d_in[5];
    const float* gat_b    = (const float*)d_in[6];
    const float* w1       = (const float*)d_in[7];
    const float* b1       = (const float*)d_in[8];
    const float* w2       = (const float*)d_in[9];
    const float* b2       = (const float*)d_in[10];
    const float* ln1g     = (const float*)d_in[11];
    const float* ln1b     = (const float*)d_in[12];
    const float* ln2g     = (const float*)d_in[13];
    const float* ln2b     = (const float*)d_in[14];
    float* out = (float*)d_out;

    const int N = in_sizes[0] / HID;       // 20000
    const int E = in_sizes[2] / 2;         // 320000
    const int* e_src = edge;
    const int* e_dst = edge + E;

    char* p = (char*)d_ws;
    auto alloc = [&](size_t bytes) {
        char* r = p;
        p += (bytes + 255) & ~(size_t)255;
        return (void*)r;
    };
    const int NPAD = N + 64;               // pad: unguarded GEMM A-staging reads past M
    __hip_bfloat16* hb     = (__hip_bfloat16*)alloc((size_t)NPAD * C_DIM * 2);
    __hip_bfloat16* xhb    = (__hip_bfloat16*)alloc((size_t)N * C_DIM * 2);  // gemm1 out
    __hip_bfloat16* midb   = (__hip_bfloat16*)alloc((size_t)N * FF_DIM * 2);
    float*          a_s    = (float*)alloc((size_t)N * HEADS * 4);
    float*          a_d    = (float*)alloc((size_t)N * HEADS * 4);
    int*            counts = (int*)alloc((size_t)N * 4);
    int*            offs   = (int*)alloc((size_t)(N + 1) * 4);
    int*            cursor = (int*)alloc((size_t)N * 4);
    int*            csr    = (int*)alloc((size_t)E * 4);
    __hip_bfloat16* WT     = (__hip_bfloat16*)alloc((size_t)NLAYERS * C_DIM * C_DIM * 2);
    __hip_bfloat16* w1T    = (__hip_bfloat16*)alloc((size_t)NLAYERS * C_DIM * FF_DIM * 2);
    __hip_bfloat16* w2T    = (__hip_bfloat16*)alloc((size_t)NLAYERS * FF_DIM * C_DIM * 2);

    {
        int total = N * C_DIM;
        concat_kernel<<<(total + 255) / 256, 256, 0, stream>>>(hf, hs, hb, N);
    }
    transp_bf16_kernel<<<dim3(C_DIM / 32, C_DIM / 32, NLAYERS), 256, 0, stream>>>(W, WT, C_DIM, C_DIM);
    transp_bf16_kernel<<<dim3(FF_DIM / 32, C_DIM / 32, NLAYERS), 256, 0, stream>>>(w1, w1T, C_DIM, FF_DIM);
    transp_bf16_kernel<<<dim3(C_DIM / 32, FF_DIM / 32, NLAYERS), 256, 0, stream>>>(w2, w2T, FF_DIM, C_DIM);

    zero_i32_kernel<<<(N + 255) / 256, 256, 0, stream>>>(counts, N);
    hist_kernel<<<(E + 255) / 256, 256, 0, stream>>>(e_dst, counts, E);
    scan_kernel<<<1, 1024, 0, stream>>>(counts, offs, cursor, N);
    fill_kernel<<<(E + 255) / 256, 256, 0, stream>>>(e_src, e_dst, cursor, csr, E);

    const int gm = (N + GBM - 1) / GBM;   // 313
    const int gf = (N + FBM - 1) / FBM;   // 625

    for (int l = 0; l < NLAYERS; ++l) {
        const __hip_bfloat16* Wl  = WT  + (size_t)l * C_DIM * C_DIM;
        const __hip_bfloat16* w1l = w1T + (size_t)l * C_DIM * FF_DIM;
        const __hip_bfloat16* w2l = w2T + (size_t)l * FF_DIM * C_DIM;
        const float* asl  = att_src + (size_t)l * C_DIM;
        const float* adl  = att_dst + (size_t)l * C_DIM;
        const float* gbl  = gat_b + (size_t)l * C_DIM;
        const float* b1l  = b1 + (size_t)l * FF_DIM;
        const float* b2l  = b2 + (size_t)l * C_DIM;
        const float* g1l  = ln1g + (size_t)l * C_DIM;
        const float* be1l = ln1b + (size_t)l * C_DIM;
        const float* g2l  = ln2g + (size_t)l * C_DIM;
        const float* be2l = ln2b + (size_t)l * C_DIM;

        // xhb = hb @ W[l] (bf16 out) + fused a_s/a_d epilogue
        gemm_bf16_kernel<<<dim3(gm, C_DIM / GBN), 256, 0, stream>>>(
            hb, Wl, nullptr, xhb, asl, adl, a_s, a_d, N, C_DIM, C_DIM, 0);
        // fused exp-weights + softmax-agg + bias + residual + LN1 (hb in place)
        agg_kernel<<<(N + 3) / 4, 256, 0, stream>>>(
            xhb, a_s, a_d, csr, offs, gbl, g1l, be1l, hb, N);
        // mid = relu(hb @ w1 + b1)  (bf16 out)
        gemm_bf16_kernel<<<dim3(gm, FF_DIM / GBN), 256, 0, stream>>>(
            hb, w1l, b1l, midb, nullptr, nullptr, nullptr, nullptr,
            N, FF_DIM, C_DIM, 1);
        // hb = LN(mid @ w2 + b2 + hb)  [fused gemm3+ln2; final layer -> out]
        gemm3_ln_kernel<<<gf, 256, 0, stream>>>(
            midb, w2l, b2l, g2l, be2l, hb,
            (l == NLAYERS - 1) ? out : nullptr, N);
    }
}

// Round 12
// 1128.151 us; speedup vs baseline: 1.0394x; 1.0130x over previous
//
#include <hip/hip_runtime.h>
#include <hip/hip_bf16.h>
#include <math.h>

// Problem dims (fixed by reference)
#define C_DIM 256      // h width
#define HID 128
#define HEADS 4
#define OC 64          // per-head out channels
#define FF_DIM 512
#define NLAYERS 12

constexpr float LN_EPS = 1e-5f;
constexpr float SLOPE  = 0.2f;

typedef __attribute__((ext_vector_type(4))) float f32x4;
typedef __attribute__((ext_vector_type(8))) short bf16x8_t;
typedef __attribute__((ext_vector_type(4))) int i32x4;

__device__ __forceinline__ float leaky(float x) { return x > 0.f ? x : SLOPE * x; }

__device__ __forceinline__ float bf2f(unsigned short u) {
    union { unsigned i; float f; } v; v.i = ((unsigned)u) << 16; return v.f;
}
__device__ __forceinline__ void bf2x(unsigned u, float& lo, float& hi) {
    union { unsigned i; float f; } a, b;
    a.i = u << 16; b.i = u & 0xffff0000u;
    lo = a.f; hi = b.f;
}
__device__ __forceinline__ unsigned packbf(float lo, float hi) {
    unsigned a = __bfloat16_as_ushort(__float2bfloat16(lo));
    unsigned b = __bfloat16_as_ushort(__float2bfloat16(hi));
    return a | (b << 16);
}

// ---------------------------------------------------------------------------
// Small utility kernels
// ---------------------------------------------------------------------------
__global__ void zero_i32_kernel(int* __restrict__ p, int n) {
    int i = blockIdx.x * blockDim.x + threadIdx.x;
    if (i < n) p[i] = 0;
}

// bf16-only residual stream: concat writes hb only. Vectorized (R12): 4
// channels/thread, float4 in -> ushort4 out. HID=128 divisible by 4, so a
// thread's 4 channels never straddle the hf/hs boundary.
__global__ void concat_kernel(const float* __restrict__ hf, const float* __restrict__ hs,
                              __hip_bfloat16* __restrict__ hb, int Nn) {
    int idx = blockIdx.x * blockDim.x + threadIdx.x;   // quad index
    int total = Nn * (C_DIM / 4);
    if (idx < total) {
        int n = idx >> 6;              // C_DIM/4 = 64 quads per row
        int c4 = (idx & 63) * 4;
        float4 v = (c4 < HID)
            ? *(const float4*)&hf[(size_t)n * HID + c4]
            : *(const float4*)&hs[(size_t)n * HID + (c4 - HID)];
        ushort4 o;
        o.x = __bfloat16_as_ushort(__float2bfloat16(v.x));
        o.y = __bfloat16_as_ushort(__float2bfloat16(v.y));
        o.z = __bfloat16_as_ushort(__float2bfloat16(v.z));
        o.w = __bfloat16_as_ushort(__float2bfloat16(v.w));
        *(ushort4*)&((unsigned short*)hb)[(size_t)n * C_DIM + c4] = o;
    }
}

// Transpose + convert weights: in [L][K][N] fp32 -> out [L][N][K] bf16
__global__ void transp_bf16_kernel(const float* __restrict__ in,
                                   __hip_bfloat16* __restrict__ out, int K, int N) {
    __shared__ float t[32][33];
    const float* inl = in + (size_t)blockIdx.z * K * N;
    __hip_bfloat16* outl = out + (size_t)blockIdx.z * K * N;
    int kb = blockIdx.y * 32, nb = blockIdx.x * 32;
    int tx = threadIdx.x & 31, ty = threadIdx.x >> 5; // 32x8
    #pragma unroll
    for (int r = 0; r < 32; r += 8)
        t[ty + r][tx] = inl[(size_t)(kb + ty + r) * N + nb + tx];
    __syncthreads();
    #pragma unroll
    for (int r = 0; r < 32; r += 8)
        outl[(size_t)(nb + ty + r) * K + kb + tx] = __float2bfloat16(t[tx][ty + r]);
}

// ---------------------------------------------------------------------------
// CSR build: histogram of dst, 3-phase parallel exclusive scan (R12 — the
// old single-block scan serialized 20 x (3 barriers + thread-0 16-step loop)
// on ONE CU, ~25-30us), fill src lists.
// ---------------------------------------------------------------------------
__global__ void hist_kernel(const int* __restrict__ dst, int* __restrict__ counts, int E) {
    int e = blockIdx.x * blockDim.x + threadIdx.x;
    if (e < E) atomicAdd(&counts[dst[e]], 1);
}

// Phase 1: per-block (1024 thr) local exclusive scan; block total -> bsum.
__global__ void scan1_kernel(const int* __restrict__ counts, int* __restrict__ offsets,
                             int* __restrict__ bsum, int n) {
    __shared__ int wsum[16];
    const int lane = threadIdx.x & 63, wid = threadIdx.x >> 6;
    int i = blockIdx.x * 1024 + (int)threadIdx.x;
    int v = (i < n) ? counts[i] : 0;
    int x = v;
    #pragma unroll
    for (int off = 1; off < 64; off <<= 1) {
        int t = __shfl_up(x, off);
        if (lane >= off) x += t;
    }
    if (lane == 63) wsum[wid] = x;
    __syncthreads();
    if (threadIdx.x == 0) {
        int acc = 0;
        #pragma unroll
        for (int w = 0; w < 16; ++w) { int t = wsum[w]; wsum[w] = acc; acc += t; }
        bsum[blockIdx.x] = acc;
    }
    __syncthreads();
    if (i < n) offsets[i] = wsum[wid] + x - v;
}

// Phase 2: exclusive scan of block sums (nb ~ 20; single thread is fine).
__global__ void scan2_kernel(int* __restrict__ bsum, int* __restrict__ offsets,
                             int nb, int n) {
    if (threadIdx.x == 0) {
        int acc = 0;
        for (int b = 0; b < nb; ++b) { int t = bsum[b]; bsum[b] = acc; acc += t; }
        offsets[n] = acc;
    }
}

// Phase 3: add block offset; fill cursor.
__global__ void scan3_kernel(int* __restrict__ offsets, int* __restrict__ cursor,
                             const int* __restrict__ bsum, int n) {
    int i = blockIdx.x * blockDim.x + threadIdx.x;
    if (i < n) {
        int o = offsets[i] + bsum[i >> 10];
        offsets[i] = o;
        cursor[i] = o;
    }
}

__global__ void fill_kernel(const int* __restrict__ src, const int* __restrict__ dst,
                            int* __restrict__ cursor, int* __restrict__ csr_src, int E) {
    int e = blockIdx.x * blockDim.x + threadIdx.x;
    if (e < E) {
        int d = dst[e];
        int p = atomicAdd(&cursor[d], 1);
        csr_src[p] = src[e];
    }
}

// ---------------------------------------------------------------------------
// bf16 MFMA GEMM (R7-verified BEST state, 1134.7us): 64x128 tile, BK=64,
// 256 thr = 4 waves (2m x 2n), each wave 32 rows x 64 cols (acc 2x4).
// Register staging -> LDS (GLS=72 pad, 2-way alias free). A-staging
// UNGUARDED: A buffers padded +64 rows. Runtime K loop.
// Sharp local optimum — regressed variants: 128^2 gl_lds (R0 1297),
// 2-phase dbuf (R3 1357), FBM=64 (R6 1261), 512-thr (R8 1173),
// K-unroll (R9 1164), staging rebalance (R10 1147).
// gemm1 attention epilogue: wave's 64 cols = exactly one head -> pure
// in-wave 16-lane reduce, no LDS combine, no extra barrier.
// C/D: col=lane&15, row=(lane>>4)*4+reg  [verified m89/m91]
// ---------------------------------------------------------------------------
#define GBM 64
#define GBN 128
#define GBK 64
#define GLS 72   // LDS row stride (shorts): 144B; 2-way bank alias = free

__global__ __launch_bounds__(256) void gemm_bf16_kernel(
    const __hip_bfloat16* __restrict__ A,   // [M x K] bf16 row-major (rows padded +64)
    const __hip_bfloat16* __restrict__ BT,  // [N x K] bf16 row-major (B^T)
    const float* __restrict__ bias,         // [N] or null
    __hip_bfloat16* __restrict__ Cb,        // bf16 out
    const float* __restrict__ attS,         // [N] att_src slice or null
    const float* __restrict__ attD,
    float* __restrict__ aS,                 // [M x HEADS] out or null
    float* __restrict__ aD,
    int M, int N, int K, int relu)
{
    __shared__ short As[GBM * GLS];          // 9.2 KB
    __shared__ short Bs[GBN * GLS];          // 18.4 KB
    const int tid = threadIdx.x;
    const int wave = tid >> 6, lane = tid & 63;
    const int lr = lane & 15, lq = lane >> 4;
    const int wm = (wave >> 1) * 32, wn = (wave & 1) * 64;
    const int row0 = blockIdx.x * GBM, col0 = blockIdx.y * GBN;

    const int sra = tid >> 2;             // A staging row 0..63
    const int sca = (tid & 3) * 16;       // shorts: 0,16,32,48
    const int srb = tid >> 1;             // B staging row 0..127
    const int scb = (tid & 1) * 32;       // shorts: 0,32

    f32x4 acc[2][4] = {};

    for (int k0 = 0; k0 < K; k0 += GBK) {
        const __hip_bfloat16* ap = &A[(size_t)(row0 + sra) * K + k0 + sca];
        i32x4 va0 = *(const i32x4*)ap;
        i32x4 va1 = *(const i32x4*)(ap + 8);
        const __hip_bfloat16* bp = &BT[(size_t)(col0 + srb) * K + k0 + scb];
        i32x4 vb0 = *(const i32x4*)bp;
        i32x4 vb1 = *(const i32x4*)(bp + 8);
        i32x4 vb2 = *(const i32x4*)(bp + 16);
        i32x4 vb3 = *(const i32x4*)(bp + 24);
        *(i32x4*)&As[sra * GLS + sca] = va0;
        *(i32x4*)&As[sra * GLS + sca + 8] = va1;
        *(i32x4*)&Bs[srb * GLS + scb] = vb0;
        *(i32x4*)&Bs[srb * GLS + scb + 8] = vb1;
        *(i32x4*)&Bs[srb * GLS + scb + 16] = vb2;
        *(i32x4*)&Bs[srb * GLS + scb + 24] = vb3;
        __syncthreads();

        #pragma unroll
        for (int ks = 0; ks < 2; ++ks) {
            bf16x8_t af[2], bfr[4];
            #pragma unroll
            for (int t = 0; t < 2; ++t)
                af[t]  = *(const bf16x8_t*)&As[(wm + t * 16 + lr) * GLS + ks * 32 + lq * 8];
            #pragma unroll
            for (int t = 0; t < 4; ++t)
                bfr[t] = *(const bf16x8_t*)&Bs[(wn + t * 16 + lr) * GLS + ks * 32 + lq * 8];
            #pragma unroll
            for (int mt = 0; mt < 2; ++mt)
                #pragma unroll
                for (int nt = 0; nt < 4; ++nt)
                    acc[mt][nt] = __builtin_amdgcn_mfma_f32_16x16x32_bf16(
                        af[mt], bfr[nt], acc[mt][nt], 0, 0, 0);
        }
        __syncthreads();
    }

    float bv[4];
    #pragma unroll
    for (int nt = 0; nt < 4; ++nt)
        bv[nt] = bias ? bias[col0 + wn + nt * 16 + lr] : 0.f;

    #pragma unroll
    for (int mt = 0; mt < 2; ++mt) {
        #pragma unroll
        for (int r = 0; r < 4; ++r) {
            int grow = row0 + wm + mt * 16 + lq * 4 + r;
            if (grow >= M) continue;
            #pragma unroll
            for (int nt = 0; nt < 4; ++nt) {
                float v = acc[mt][nt][r] + bv[nt];
                if (relu) v = fmaxf(v, 0.f);
                Cb[(size_t)grow * N + col0 + wn + nt * 16 + lr] = __float2bfloat16(v);
            }
        }
    }

    // Fused attention-coefficient epilogue (gemm1 only).
    // Wave's 64 cols = exactly one head: pure in-wave reduce, no LDS.
    if (aS) {
        const int head = (col0 + wn) >> 6;
        float atS[4], atD[4];
        #pragma unroll
        for (int nt = 0; nt < 4; ++nt) {
            int c = col0 + wn + nt * 16 + lr;
            atS[nt] = attS[c];
            atD[nt] = attD[c];
        }
        #pragma unroll
        for (int mt = 0; mt < 2; ++mt) {
            #pragma unroll
            for (int r = 0; r < 4; ++r) {
                float vs = acc[mt][0][r] * atS[0] + acc[mt][1][r] * atS[1]
                         + acc[mt][2][r] * atS[2] + acc[mt][3][r] * atS[3];
                float vd = acc[mt][0][r] * atD[0] + acc[mt][1][r] * atD[1]
                         + acc[mt][2][r] * atD[2] + acc[mt][3][r] * atD[3];
                #pragma unroll
                for (int off = 1; off < 16; off <<= 1) {
                    vs += __shfl_xor(vs, off);
                    vd += __shfl_xor(vd, off);
                }
                if (lr == 0) {
                    int grow = row0 + wm + mt * 16 + lq * 4 + r;
                    if (grow < M) {
                        aS[grow * HEADS + head] = vs;
                        aD[grow * HEADS + head] = vd;
                    }
                }
            }
        }
    }
}

// ---------------------------------------------------------------------------
// gemm3 + ln2 fused (R7-verified, FBM=32, 256 thr): fbuf-free.
// C = mid @ w2 + b2; val = C + hb; LN; write hb (final layer: split fp32).
// Block = 32 rows x 256 cols (full N), K=512, grid 625 (M=625*32 exact).
// 4 waves split columns; acc 2x4 = 32 VGPRs. Regressed variants: FBM=64
// (R6), 512-thr (R8), deguarded A-staging rebalance (R10).
// Row-LN: per-wave 16-lane shfl reduce -> 1KB LDS combine of 4 col-quarters.
// ---------------------------------------------------------------------------
#define FBM 32

__global__ __launch_bounds__(256) void gemm3_ln_kernel(
    const __hip_bfloat16* __restrict__ A,   // midb [M x FF_DIM]
    const __hip_bfloat16* __restrict__ BT,  // w2T  [C_DIM x FF_DIM]
    const float* __restrict__ bias,         // b2 [C_DIM]
    const float* __restrict__ ln_g, const float* __restrict__ ln_b,
    __hip_bfloat16* __restrict__ hb,        // residual in; LN out (non-final)
    float* __restrict__ out_split,          // final layer: split fp32 out
    int M)
{
    __shared__ short As[FBM * GLS];         // 4.5 KB
    __shared__ short Bs[C_DIM * GLS];       // 36 KB
    __shared__ float rsum[2][FBM][4];       // [s1|s2][row][col-quarter]

    const int tid = threadIdx.x;
    const int wave = tid >> 6, lane = tid & 63;
    const int lr = lane & 15, lq = lane >> 4;
    const int wn = wave * 64;               // column base for this wave
    const int row0 = blockIdx.x * FBM;

    const int sr = tid >> 2;                // 0..63
    const int sc = (tid & 3) * 16;

    f32x4 acc[2][4] = {};

    for (int k0 = 0; k0 < FF_DIM; k0 += GBK) {
        if (sr < FBM) {
            const __hip_bfloat16* ap = &A[(size_t)(row0 + sr) * FF_DIM + k0 + sc];
            *(i32x4*)&As[sr * GLS + sc] = *(const i32x4*)ap;
            *(i32x4*)&As[sr * GLS + sc + 8] = *(const i32x4*)(ap + 8);
        }
        #pragma unroll
        for (int rb = 0; rb < 4; ++rb) {
            const int br = rb * 64 + sr;
            const __hip_bfloat16* bp = &BT[(size_t)br * FF_DIM + k0 + sc];
            *(i32x4*)&Bs[br * GLS + sc] = *(const i32x4*)bp;
            *(i32x4*)&Bs[br * GLS + sc + 8] = *(const i32x4*)(bp + 8);
        }
        __syncthreads();

        #pragma unroll
        for (int ks = 0; ks < 2; ++ks) {
            bf16x8_t af[2], bfr[4];
            #pragma unroll
            for (int mt = 0; mt < 2; ++mt)
                af[mt] = *(const bf16x8_t*)&As[(mt * 16 + lr) * GLS + ks * 32 + lq * 8];
            #pragma unroll
            for (int nt = 0; nt < 4; ++nt)
                bfr[nt] = *(const bf16x8_t*)&Bs[(wn + nt * 16 + lr) * GLS + ks * 32 + lq * 8];
            #pragma unroll
            for (int mt = 0; mt < 2; ++mt)
                #pragma unroll
                for (int nt = 0; nt < 4; ++nt)
                    acc[mt][nt] = __builtin_amdgcn_mfma_f32_16x16x32_bf16(
                        af[mt], bfr[nt], acc[mt][nt], 0, 0, 0);
        }
        __syncthreads();
    }

    float bv[4];
    #pragma unroll
    for (int nt = 0; nt < 4; ++nt)
        bv[nt] = bias[wn + nt * 16 + lr];

    // val = C + b2 + residual; per-row partial sums over this wave's 64 cols
    const unsigned short* hbp = (const unsigned short*)hb;
    #pragma unroll
    for (int mt = 0; mt < 2; ++mt) {
        #pragma unroll
        for (int r = 0; r < 4; ++r) {
            const int rb = mt * 16 + lq * 4 + r;      // 0..31
            const int grow = row0 + rb;
            float s1 = 0.f, s2 = 0.f;
            #pragma unroll
            for (int nt = 0; nt < 4; ++nt) {
                float res = (grow < M)
                    ? bf2f(hbp[(size_t)grow * C_DIM + wn + nt * 16 + lr]) : 0.f;
                float v = acc[mt][nt][r] + bv[nt] + res;
                acc[mt][nt][r] = v;                   // keep for normalize phase
                s1 += v; s2 += v * v;
            }
            #pragma unroll
            for (int off = 1; off < 16; off <<= 1) {
                s1 += __shfl_xor(s1, off);
                s2 += __shfl_xor(s2, off);
            }
            if (lr == 0) {
                rsum[0][rb][wave] = s1;
                rsum[1][rb][wave] = s2;
            }
        }
    }
    __syncthreads();

    float g[4], bb[4];
    #pragma unroll
    for (int nt = 0; nt < 4; ++nt) {
        g[nt]  = ln_g[wn + nt * 16 + lr];
        bb[nt] = ln_b[wn + nt * 16 + lr];
    }

    #pragma unroll
    for (int mt = 0; mt < 2; ++mt) {
        #pragma unroll
        for (int r = 0; r < 4; ++r) {
            const int rb = mt * 16 + lq * 4 + r;
            const int grow = row0 + rb;
            if (grow >= M) continue;
            float s1 = (rsum[0][rb][0] + rsum[0][rb][1]) + (rsum[0][rb][2] + rsum[0][rb][3]);
            float s2 = (rsum[1][rb][0] + rsum[1][rb][1]) + (rsum[1][rb][2] + rsum[1][rb][3]);
            float mean = s1 * (1.0f / C_DIM);
            float inv = rsqrtf(s2 * (1.0f / C_DIM) - mean * mean + LN_EPS);
            if (out_split) {
                #pragma unroll
                for (int nt = 0; nt < 4; ++nt) {
                    float o = (acc[mt][nt][r] - mean) * inv * g[nt] + bb[nt];
                    int c = wn + nt * 16 + lr;
                    size_t off_ = (c < HID) ? ((size_t)grow * HID + c)
                                            : ((size_t)M * HID + (size_t)grow * HID + (c - HID));
                    out_split[off_] = o;
                }
            } else {
                #pragma unroll
                for (int nt = 0; nt < 4; ++nt) {
                    float o = (acc[mt][nt][r] - mean) * inv * g[nt] + bb[nt];
                    ((unsigned short*)hb)[(size_t)grow * C_DIM + wn + nt * 16 + lr] =
                        __bfloat16_as_ushort(__float2bfloat16(o));
                }
            }
        }
    }
}

// ---------------------------------------------------------------------------
// Fused GAT: per-edge exp weights in-loop + weighted bf16 gather + bias +
// residual (bf16 hb) + LN1. One WAVE per node; lane owns 8 channels (16B
// gathers); two 32-lane halves process disjoint edge halves; combined via
// shfl_xor(32). hb updated in place (bf16-only residual stream).
// ---------------------------------------------------------------------------
__global__ __launch_bounds__(256) void agg_kernel(
    const __hip_bfloat16* __restrict__ xhb, const float* __restrict__ a_s,
    const float* __restrict__ a_d, const int* __restrict__ csr,
    const int* __restrict__ offs, const float* __restrict__ gat_b,
    const float* __restrict__ ln_g, const float* __restrict__ ln_b,
    __hip_bfloat16* __restrict__ hb, int Nn)
{
    const int lane = threadIdx.x & 63;
    const int n = __builtin_amdgcn_readfirstlane(blockIdx.x * 4 + (threadIdx.x >> 6));
    if (n >= Nn) return;
    const int half = lane >> 5;
    const int sl = lane & 31;
    const int head = sl >> 3;            // 8 lanes per head
    const int c0 = sl * 8;               // 8 channels per lane
    const unsigned* x = (const unsigned*)xhb;   // packed bf16 pairs
    const size_t rowp = (size_t)n * (C_DIM / 2) + (c0 >> 1);

    const float ad = a_d[n * 4 + head];

    const int beg = offs[n], end = offs[n + 1];
    const int ne = end - beg;
    const int nh0 = (ne + 1) >> 1;
    int ih  = half ? (beg + nh0) : beg;
    int cnt = half ? (ne - nh0) : nh0;

    // residual from bf16 hb (issue early)
    i32x4 rv = *(const i32x4*)&((const unsigned*)hb)[rowp];

    float acc[8] = {};
    float z = 0.f;

    {
        float wself = __expf(leaky(a_s[n * 4 + head] + ad));
        if (half) {
            i32x4 xv = *(const i32x4*)&x[rowp];
            #pragma unroll
            for (int q = 0; q < 4; ++q) {
                float lo, hi; bf2x((unsigned)xv[q], lo, hi);
                acc[2 * q]     = wself * lo;
                acc[2 * q + 1] = wself * hi;
            }
            z = wself;
        }
    }

    for (; cnt >= 4; cnt -= 4, ih += 4) {
        int s0 = csr[ih], s1 = csr[ih + 1], s2 = csr[ih + 2], s3 = csr[ih + 3];
        float w0 = __expf(leaky(a_s[s0 * 4 + head] + ad));
        float w1 = __expf(leaky(a_s[s1 * 4 + head] + ad));
        float w2 = __expf(leaky(a_s[s2 * 4 + head] + ad));
        float w3 = __expf(leaky(a_s[s3 * 4 + head] + ad));
        i32x4 x0 = *(const i32x4*)&x[(size_t)s0 * (C_DIM / 2) + (c0 >> 1)];
        i32x4 x1 = *(const i32x4*)&x[(size_t)s1 * (C_DIM / 2) + (c0 >> 1)];
        i32x4 x2 = *(const i32x4*)&x[(size_t)s2 * (C_DIM / 2) + (c0 >> 1)];
        i32x4 x3 = *(const i32x4*)&x[(size_t)s3 * (C_DIM / 2) + (c0 >> 1)];
        #pragma unroll
        for (int q = 0; q < 4; ++q) {
            float lo, hi;
            bf2x((unsigned)x0[q], lo, hi);
            acc[2 * q] += w0 * lo; acc[2 * q + 1] += w0 * hi;
            bf2x((unsigned)x1[q], lo, hi);
            acc[2 * q] += w1 * lo; acc[2 * q + 1] += w1 * hi;
            bf2x((unsigned)x2[q], lo, hi);
            acc[2 * q] += w2 * lo; acc[2 * q + 1] += w2 * hi;
            bf2x((unsigned)x3[q], lo, hi);
            acc[2 * q] += w3 * lo; acc[2 * q + 1] += w3 * hi;
        }
        z += (w0 + w1) + (w2 + w3);
    }
    for (; cnt > 0; --cnt, ++ih) {
        int s0 = csr[ih];
        float w0 = __expf(leaky(a_s[s0 * 4 + head] + ad));
        i32x4 x0 = *(const i32x4*)&x[(size_t)s0 * (C_DIM / 2) + (c0 >> 1)];
        #pragma unroll
        for (int q = 0; q < 4; ++q) {
            float lo, hi; bf2x((unsigned)x0[q], lo, hi);
            acc[2 * q] += w0 * lo; acc[2 * q + 1] += w0 * hi;
        }
        z += w0;
    }

    #pragma unroll
    for (int j = 0; j < 8; ++j) acc[j] += __shfl_xor(acc[j], 32);
    z += __shfl_xor(z, 32);

    float res[8];
    #pragma unroll
    for (int q = 0; q < 4; ++q) bf2x((unsigned)rv[q], res[2 * q], res[2 * q + 1]);

    float4 gb0 = *(const float4*)&gat_b[c0];
    float4 gb1 = *(const float4*)&gat_b[c0 + 4];
    float gb[8] = {gb0.x, gb0.y, gb0.z, gb0.w, gb1.x, gb1.y, gb1.z, gb1.w};
    float rz = 1.0f / z;
    float val[8];
    #pragma unroll
    for (int j = 0; j < 8; ++j) val[j] = acc[j] * rz + gb[j] + res[j];

    // LN: each channel appears on 2 lanes -> normalize by 512.
    float s1 = 0.f, s2 = 0.f;
    #pragma unroll
    for (int j = 0; j < 8; ++j) { s1 += val[j]; s2 += val[j] * val[j]; }
    #pragma unroll
    for (int off = 1; off < 64; off <<= 1) {
        s1 += __shfl_xor(s1, off);
        s2 += __shfl_xor(s2, off);
    }
    float mean = s1 * (1.0f / (2 * C_DIM));
    float inv = rsqrtf(s2 * (1.0f / (2 * C_DIM)) - mean * mean + LN_EPS);

    if (half == 0) {
        float4 g0 = *(const float4*)&ln_g[c0];
        float4 g1 = *(const float4*)&ln_g[c0 + 4];
        float4 bb0 = *(const float4*)&ln_b[c0];
        float4 bb1 = *(const float4*)&ln_b[c0 + 4];
        float g[8] = {g0.x, g0.y, g0.z, g0.w, g1.x, g1.y, g1.z, g1.w};
        float bb[8] = {bb0.x, bb0.y, bb0.z, bb0.w, bb1.x, bb1.y, bb1.z, bb1.w};
        float o[8];
        #pragma unroll
        for (int j = 0; j < 8; ++j) o[j] = (val[j] - mean) * inv * g[j] + bb[j];
        i32x4 ob;
        ob[0] = (int)packbf(o[0], o[1]);
        ob[1] = (int)packbf(o[2], o[3]);
        ob[2] = (int)packbf(o[4], o[5]);
        ob[3] = (int)packbf(o[6], o[7]);
        *(i32x4*)&((unsigned*)hb)[rowp] = ob;
    }
}

// ---------------------------------------------------------------------------
// Host launch
// ---------------------------------------------------------------------------
extern "C" void kernel_launch(void* const* d_in, const int* in_sizes, int n_in,
                              void* d_out, int out_size, void* d_ws, size_t ws_size,
                              hipStream_t stream)
{
    const float* hf       = (const float*)d_in[0];
    const float* hs       = (const float*)d_in[1];
    const int*   edge     = (const int*)  d_in[2];
    const float* W        = (const float*)d_in[3];
    const float* att_src  = (const float*)d_in[4];
    const float* att_dst  = (const float*)d_in[5];
    const float* gat_b    = (const float*)d_in[6];
    const float* w1       = (const float*)d_in[7];
    const float* b1       = (const float*)d_in[8];
    const float* w2       = (const float*)d_in[9];
    const float* b2       = (const float*)d_in[10];
    const float* ln1g     = (const float*)d_in[11];
    const float* ln1b     = (const float*)d_in[12];
    const float* ln2g     = (const float*)d_in[13];
    const float* ln2b     = (const float*)d_in[14];
    float* out = (float*)d_out;

    const int N = in_sizes[0] / HID;       // 20000
    const int E = in_sizes[2] / 2;         // 320000
    const int* e_src = edge;
    const int* e_dst = edge + E;

    char* p = (char*)d_ws;
    auto alloc = [&](size_t bytes) {
        char* r = p;
        p += (bytes + 255) & ~(size_t)255;
        return (void*)r;
    };
    const int NPAD = N + 64;               // pad: unguarded GEMM A-staging reads past M
    const int NB   = (N + 1023) / 1024;    // scan phase-1 blocks (20)
    __hip_bfloat16* hb     = (__hip_bfloat16*)alloc((size_t)NPAD * C_DIM * 2);
    __hip_bfloat16* xhb    = (__hip_bfloat16*)alloc((size_t)N * C_DIM * 2);  // gemm1 out
    __hip_bfloat16* midb   = (__hip_bfloat16*)alloc((size_t)N * FF_DIM * 2);
    float*          a_s    = (float*)alloc((size_t)N * HEADS * 4);
    float*          a_d    = (float*)alloc((size_t)N * HEADS * 4);
    int*            counts = (int*)alloc((size_t)N * 4);
    int*            offs   = (int*)alloc((size_t)(N + 1) * 4);
    int*            cursor = (int*)alloc((size_t)N * 4);
    int*            csr    = (int*)alloc((size_t)E * 4);
    int*            bsum   = (int*)alloc((size_t)NB * 4);
    __hip_bfloat16* WT     = (__hip_bfloat16*)alloc((size_t)NLAYERS * C_DIM * C_DIM * 2);
    __hip_bfloat16* w1T    = (__hip_bfloat16*)alloc((size_t)NLAYERS * C_DIM * FF_DIM * 2);
    __hip_bfloat16* w2T    = (__hip_bfloat16*)alloc((size_t)NLAYERS * FF_DIM * C_DIM * 2);

    {
        int total = N * (C_DIM / 4);
        concat_kernel<<<(total + 255) / 256, 256, 0, stream>>>(hf, hs, hb, N);
    }
    transp_bf16_kernel<<<dim3(C_DIM / 32, C_DIM / 32, NLAYERS), 256, 0, stream>>>(W, WT, C_DIM, C_DIM);
    transp_bf16_kernel<<<dim3(FF_DIM / 32, C_DIM / 32, NLAYERS), 256, 0, stream>>>(w1, w1T, C_DIM, FF_DIM);
    transp_bf16_kernel<<<dim3(C_DIM / 32, FF_DIM / 32, NLAYERS), 256, 0, stream>>>(w2, w2T, FF_DIM, C_DIM);

    zero_i32_kernel<<<(N + 255) / 256, 256, 0, stream>>>(counts, N);
    hist_kernel<<<(E + 255) / 256, 256, 0, stream>>>(e_dst, counts, E);
    scan1_kernel<<<NB, 1024, 0, stream>>>(counts, offs, bsum, N);
    scan2_kernel<<<1, 64, 0, stream>>>(bsum, offs, NB, N);
    scan3_kernel<<<(N + 255) / 256, 256, 0, stream>>>(offs, cursor, bsum, N);
    fill_kernel<<<(E + 255) / 256, 256, 0, stream>>>(e_src, e_dst, cursor, csr, E);

    const int gm = (N + GBM - 1) / GBM;   // 313
    const int gf = (N + FBM - 1) / FBM;   // 625

    for (int l = 0; l < NLAYERS; ++l) {
        const __hip_bfloat16* Wl  = WT  + (size_t)l * C_DIM * C_DIM;
        const __hip_bfloat16* w1l = w1T + (size_t)l * C_DIM * FF_DIM;
        const __hip_bfloat16* w2l = w2T + (size_t)l * FF_DIM * C_DIM;
        const float* asl  = att_src + (size_t)l * C_DIM;
        const float* adl  = att_dst + (size_t)l * C_DIM;
        const float* gbl  = gat_b + (size_t)l * C_DIM;
        const float* b1l  = b1 + (size_t)l * FF_DIM;
        const float* b2l  = b2 + (size_t)l * C_DIM;
        const float* g1l  = ln1g + (size_t)l * C_DIM;
        const float* be1l = ln1b + (size_t)l * C_DIM;
        const float* g2l  = ln2g + (size_t)l * C_DIM;
        const float* be2l = ln2b + (size_t)l * C_DIM;

        // xhb = hb @ W[l] (bf16 out) + fused a_s/a_d epilogue
        gemm_bf16_kernel<<<dim3(gm, C_DIM / GBN), 256, 0, stream>>>(
            hb, Wl, nullptr, xhb, asl, adl, a_s, a_d, N, C_DIM, C_DIM, 0);
        // fused exp-weights + softmax-agg + bias + residual + LN1 (hb in place)
        agg_kernel<<<(N + 3) / 4, 256, 0, stream>>>(
            xhb, a_s, a_d, csr, offs, gbl, g1l, be1l, hb, N);
        // mid = relu(hb @ w1 + b1)  (bf16 out)
        gemm_bf16_kernel<<<dim3(gm, FF_DIM / GBN), 256, 0, stream>>>(
            hb, w1l, b1l, midb, nullptr, nullptr, nullptr, nullptr,
            N, FF_DIM, C_DIM, 1);
        // hb = LN(mid @ w2 + b2 + hb)  [fused gemm3+ln2; final layer -> out]
        gemm3_ln_kernel<<<gf, 256, 0, stream>>>(
            midb, w2l, b2l, g2l, be2l, hb,
            (l == NLAYERS - 1) ? out : nullptr, N);
    }
}

// Round 13
// 1085.924 us; speedup vs baseline: 1.0798x; 1.0389x over previous
//
#include <hip/hip_runtime.h>
#include <hip/hip_bf16.h>
#include <math.h>

// Problem dims (fixed by reference)
#define C_DIM 256      // h width
#define HID 128
#define HEADS 4
#define OC 64          // per-head out channels
#define FF_DIM 512
#define NLAYERS 12

constexpr float LN_EPS = 1e-5f;
constexpr float SLOPE  = 0.2f;

typedef __attribute__((ext_vector_type(4))) float f32x4;
typedef __attribute__((ext_vector_type(8))) short bf16x8_t;
typedef __attribute__((ext_vector_type(4))) int i32x4;

__device__ __forceinline__ float leaky(float x) { return x > 0.f ? x : SLOPE * x; }

__device__ __forceinline__ float bf2f(unsigned short u) {
    union { unsigned i; float f; } v; v.i = ((unsigned)u) << 16; return v.f;
}
__device__ __forceinline__ void bf2x(unsigned u, float& lo, float& hi) {
    union { unsigned i; float f; } a, b;
    a.i = u << 16; b.i = u & 0xffff0000u;
    lo = a.f; hi = b.f;
}
__device__ __forceinline__ unsigned packbf(float lo, float hi) {
    unsigned a = __bfloat16_as_ushort(__float2bfloat16(lo));
    unsigned b = __bfloat16_as_ushort(__float2bfloat16(hi));
    return a | (b << 16);
}

// ---------------------------------------------------------------------------
// Small utility kernels
// ---------------------------------------------------------------------------
// bf16-only residual stream: concat writes hb only. Vectorized (R12): 4
// channels/thread, float4 in -> ushort4 out.
__global__ void concat_kernel(const float* __restrict__ hf, const float* __restrict__ hs,
                              __hip_bfloat16* __restrict__ hb, int Nn) {
    int idx = blockIdx.x * blockDim.x + threadIdx.x;   // quad index
    int total = Nn * (C_DIM / 4);
    if (idx < total) {
        int n = idx >> 6;              // C_DIM/4 = 64 quads per row
        int c4 = (idx & 63) * 4;
        float4 v = (c4 < HID)
            ? *(const float4*)&hf[(size_t)n * HID + c4]
            : *(const float4*)&hs[(size_t)n * HID + (c4 - HID)];
        ushort4 o;
        o.x = __bfloat16_as_ushort(__float2bfloat16(v.x));
        o.y = __bfloat16_as_ushort(__float2bfloat16(v.y));
        o.z = __bfloat16_as_ushort(__float2bfloat16(v.z));
        o.w = __bfloat16_as_ushort(__float2bfloat16(v.w));
        *(ushort4*)&((unsigned short*)hb)[(size_t)n * C_DIM + c4] = o;
    }
}

// Transpose + convert weights: in [L][K][N] fp32 -> out [L][N][K] bf16
__global__ void transp_bf16_kernel(const float* __restrict__ in,
                                   __hip_bfloat16* __restrict__ out, int K, int N) {
    __shared__ float t[32][33];
    const float* inl = in + (size_t)blockIdx.z * K * N;
    __hip_bfloat16* outl = out + (size_t)blockIdx.z * K * N;
    int kb = blockIdx.y * 32, nb = blockIdx.x * 32;
    int tx = threadIdx.x & 31, ty = threadIdx.x >> 5; // 32x8
    #pragma unroll
    for (int r = 0; r < 32; r += 8)
        t[ty + r][tx] = inl[(size_t)(kb + ty + r) * N + nb + tx];
    __syncthreads();
    #pragma unroll
    for (int r = 0; r < 32; r += 8)
        outl[(size_t)(nb + ty + r) * K + kb + tx] = __float2bfloat16(t[tx][ty + r]);
}

// ---------------------------------------------------------------------------
// CSR build: histogram of dst, 3-phase parallel exclusive scan (R12),
// fill src lists. counts zeroed via hipMemsetAsync (R13).
// ---------------------------------------------------------------------------
__global__ void hist_kernel(const int* __restrict__ dst, int* __restrict__ counts, int E) {
    int e = blockIdx.x * blockDim.x + threadIdx.x;
    if (e < E) atomicAdd(&counts[dst[e]], 1);
}

// Phase 1: per-block (1024 thr) local exclusive scan; block total -> bsum.
__global__ void scan1_kernel(const int* __restrict__ counts, int* __restrict__ offsets,
                             int* __restrict__ bsum, int n) {
    __shared__ int wsum[16];
    const int lane = threadIdx.x & 63, wid = threadIdx.x >> 6;
    int i = blockIdx.x * 1024 + (int)threadIdx.x;
    int v = (i < n) ? counts[i] : 0;
    int x = v;
    #pragma unroll
    for (int off = 1; off < 64; off <<= 1) {
        int t = __shfl_up(x, off);
        if (lane >= off) x += t;
    }
    if (lane == 63) wsum[wid] = x;
    __syncthreads();
    if (threadIdx.x == 0) {
        int acc = 0;
        #pragma unroll
        for (int w = 0; w < 16; ++w) { int t = wsum[w]; wsum[w] = acc; acc += t; }
        bsum[blockIdx.x] = acc;
    }
    __syncthreads();
    if (i < n) offsets[i] = wsum[wid] + x - v;
}

// Phase 2: exclusive scan of block sums (nb ~ 20; single thread is fine).
__global__ void scan2_kernel(int* __restrict__ bsum, int* __restrict__ offsets,
                             int nb, int n) {
    if (threadIdx.x == 0) {
        int acc = 0;
        for (int b = 0; b < nb; ++b) { int t = bsum[b]; bsum[b] = acc; acc += t; }
        offsets[n] = acc;
    }
}

// Phase 3: add block offset; fill cursor.
__global__ void scan3_kernel(int* __restrict__ offsets, int* __restrict__ cursor,
                             const int* __restrict__ bsum, int n) {
    int i = blockIdx.x * blockDim.x + threadIdx.x;
    if (i < n) {
        int o = offsets[i] + bsum[i >> 10];
        offsets[i] = o;
        cursor[i] = o;
    }
}

__global__ void fill_kernel(const int* __restrict__ src, const int* __restrict__ dst,
                            int* __restrict__ cursor, int* __restrict__ csr_src, int E) {
    int e = blockIdx.x * blockDim.x + threadIdx.x;
    if (e < E) {
        int d = dst[e];
        int p = atomicAdd(&cursor[d], 1);
        csr_src[p] = src[e];
    }
}

// ---------------------------------------------------------------------------
// bf16 MFMA GEMM (R7-verified BEST geometry): 64x128 tile, BK=64, 256 thr
// = 4 waves (2m x 2n), each wave 32 rows x 64 cols (acc 2x4). Register
// staging -> LDS (GLS=72 pad, 2-way alias free). A-staging AND all output
// writes UNGUARDED (R13): A buffers padded +64 rows, output buffers
// (xhb/midb/a_s/a_d) padded too — last block's 32 pad rows are write-only
// garbage, never read. Runtime K loop.
// Sharp local optimum — regressed variants: 128^2 gl_lds (R0 1297),
// 2-phase dbuf (R3 1357), FBM=64 (R6 1261), 512-thr (R8 1173),
// K-unroll (R9 1164), staging rebalance (R10 1147).
// gemm1 attention epilogue: wave's 64 cols = exactly one head -> pure
// in-wave 16-lane reduce, no LDS combine, no extra barrier.
// C/D: col=lane&15, row=(lane>>4)*4+reg  [verified m89/m91]
// ---------------------------------------------------------------------------
#define GBM 64
#define GBN 128
#define GBK 64
#define GLS 72   // LDS row stride (shorts): 144B; 2-way bank alias = free

__global__ __launch_bounds__(256) void gemm_bf16_kernel(
    const __hip_bfloat16* __restrict__ A,   // [M x K] bf16 row-major (rows padded +64)
    const __hip_bfloat16* __restrict__ BT,  // [N x K] bf16 row-major (B^T)
    const float* __restrict__ bias,         // [N] or null
    __hip_bfloat16* __restrict__ Cb,        // bf16 out (rows padded +64)
    const float* __restrict__ attS,         // [N] att_src slice or null
    const float* __restrict__ attD,
    float* __restrict__ aS,                 // [(M+64) x HEADS] out or null
    float* __restrict__ aD,
    int M, int N, int K, int relu)
{
    __shared__ short As[GBM * GLS];          // 9.2 KB
    __shared__ short Bs[GBN * GLS];          // 18.4 KB
    const int tid = threadIdx.x;
    const int wave = tid >> 6, lane = tid & 63;
    const int lr = lane & 15, lq = lane >> 4;
    const int wm = (wave >> 1) * 32, wn = (wave & 1) * 64;
    const int row0 = blockIdx.x * GBM, col0 = blockIdx.y * GBN;

    const int sra = tid >> 2;             // A staging row 0..63
    const int sca = (tid & 3) * 16;       // shorts: 0,16,32,48
    const int srb = tid >> 1;             // B staging row 0..127
    const int scb = (tid & 1) * 32;       // shorts: 0,32

    f32x4 acc[2][4] = {};

    for (int k0 = 0; k0 < K; k0 += GBK) {
        const __hip_bfloat16* ap = &A[(size_t)(row0 + sra) * K + k0 + sca];
        i32x4 va0 = *(const i32x4*)ap;
        i32x4 va1 = *(const i32x4*)(ap + 8);
        const __hip_bfloat16* bp = &BT[(size_t)(col0 + srb) * K + k0 + scb];
        i32x4 vb0 = *(const i32x4*)bp;
        i32x4 vb1 = *(const i32x4*)(bp + 8);
        i32x4 vb2 = *(const i32x4*)(bp + 16);
        i32x4 vb3 = *(const i32x4*)(bp + 24);
        *(i32x4*)&As[sra * GLS + sca] = va0;
        *(i32x4*)&As[sra * GLS + sca + 8] = va1;
        *(i32x4*)&Bs[srb * GLS + scb] = vb0;
        *(i32x4*)&Bs[srb * GLS + scb + 8] = vb1;
        *(i32x4*)&Bs[srb * GLS + scb + 16] = vb2;
        *(i32x4*)&Bs[srb * GLS + scb + 24] = vb3;
        __syncthreads();

        #pragma unroll
        for (int ks = 0; ks < 2; ++ks) {
            bf16x8_t af[2], bfr[4];
            #pragma unroll
            for (int t = 0; t < 2; ++t)
                af[t]  = *(const bf16x8_t*)&As[(wm + t * 16 + lr) * GLS + ks * 32 + lq * 8];
            #pragma unroll
            for (int t = 0; t < 4; ++t)
                bfr[t] = *(const bf16x8_t*)&Bs[(wn + t * 16 + lr) * GLS + ks * 32 + lq * 8];
            #pragma unroll
            for (int mt = 0; mt < 2; ++mt)
                #pragma unroll
                for (int nt = 0; nt < 4; ++nt)
                    acc[mt][nt] = __builtin_amdgcn_mfma_f32_16x16x32_bf16(
                        af[mt], bfr[nt], acc[mt][nt], 0, 0, 0);
        }
        __syncthreads();
    }

    float bv[4];
    #pragma unroll
    for (int nt = 0; nt < 4; ++nt)
        bv[nt] = bias ? bias[col0 + wn + nt * 16 + lr] : 0.f;

    #pragma unroll
    for (int mt = 0; mt < 2; ++mt) {
        #pragma unroll
        for (int r = 0; r < 4; ++r) {
            int grow = row0 + wm + mt * 16 + lq * 4 + r;   // may land in pad rows
            #pragma unroll
            for (int nt = 0; nt < 4; ++nt) {
                float v = acc[mt][nt][r] + bv[nt];
                if (relu) v = fmaxf(v, 0.f);
                Cb[(size_t)grow * N + col0 + wn + nt * 16 + lr] = __float2bfloat16(v);
            }
        }
    }

    // Fused attention-coefficient epilogue (gemm1 only).
    // Wave's 64 cols = exactly one head: pure in-wave reduce, no LDS.
    if (aS) {
        const int head = (col0 + wn) >> 6;
        float atS[4], atD[4];
        #pragma unroll
        for (int nt = 0; nt < 4; ++nt) {
            int c = col0 + wn + nt * 16 + lr;
            atS[nt] = attS[c];
            atD[nt] = attD[c];
        }
        #pragma unroll
        for (int mt = 0; mt < 2; ++mt) {
            #pragma unroll
            for (int r = 0; r < 4; ++r) {
                float vs = acc[mt][0][r] * atS[0] + acc[mt][1][r] * atS[1]
                         + acc[mt][2][r] * atS[2] + acc[mt][3][r] * atS[3];
                float vd = acc[mt][0][r] * atD[0] + acc[mt][1][r] * atD[1]
                         + acc[mt][2][r] * atD[2] + acc[mt][3][r] * atD[3];
                #pragma unroll
                for (int off = 1; off < 16; off <<= 1) {
                    vs += __shfl_xor(vs, off);
                    vd += __shfl_xor(vd, off);
                }
                if (lr == 0) {
                    int grow = row0 + wm + mt * 16 + lq * 4 + r;  // pad rows OK
                    aS[grow * HEADS + head] = vs;
                    aD[grow * HEADS + head] = vd;
                }
            }
        }
    }
}

// ---------------------------------------------------------------------------
// gemm3 + ln2 fused (R7-verified, FBM=32, 256 thr): fbuf-free.
// C = mid @ w2 + b2; val = C + hb; LN; write hb (final layer: split fp32).
// Block = 32 rows x 256 cols (full N), K=512, grid 625 (M=625*32 EXACT ->
// row guards were dead code; removed, R13).
// 4 waves split columns; acc 2x4 = 32 VGPRs. Regressed variants: FBM=64
// (R6), 512-thr (R8), deguarded A-staging rebalance (R10).
// Row-LN: per-wave 16-lane shfl reduce -> 1KB LDS combine of 4 col-quarters.
// ---------------------------------------------------------------------------
#define FBM 32

__global__ __launch_bounds__(256) void gemm3_ln_kernel(
    const __hip_bfloat16* __restrict__ A,   // midb [M x FF_DIM]
    const __hip_bfloat16* __restrict__ BT,  // w2T  [C_DIM x FF_DIM]
    const float* __restrict__ bias,         // b2 [C_DIM]
    const float* __restrict__ ln_g, const float* __restrict__ ln_b,
    __hip_bfloat16* __restrict__ hb,        // residual in; LN out (non-final)
    float* __restrict__ out_split,          // final layer: split fp32 out
    int M)
{
    __shared__ short As[FBM * GLS];         // 4.5 KB
    __shared__ short Bs[C_DIM * GLS];       // 36 KB
    __shared__ float rsum[2][FBM][4];       // [s1|s2][row][col-quarter]

    const int tid = threadIdx.x;
    const int wave = tid >> 6, lane = tid & 63;
    const int lr = lane & 15, lq = lane >> 4;
    const int wn = wave * 64;               // column base for this wave
    const int row0 = blockIdx.x * FBM;

    const int sr = tid >> 2;                // 0..63
    const int sc = (tid & 3) * 16;

    f32x4 acc[2][4] = {};

    for (int k0 = 0; k0 < FF_DIM; k0 += GBK) {
        if (sr < FBM) {
            const __hip_bfloat16* ap = &A[(size_t)(row0 + sr) * FF_DIM + k0 + sc];
            *(i32x4*)&As[sr * GLS + sc] = *(const i32x4*)ap;
            *(i32x4*)&As[sr * GLS + sc + 8] = *(const i32x4*)(ap + 8);
        }
        #pragma unroll
        for (int rb = 0; rb < 4; ++rb) {
            const int br = rb * 64 + sr;
            const __hip_bfloat16* bp = &BT[(size_t)br * FF_DIM + k0 + sc];
            *(i32x4*)&Bs[br * GLS + sc] = *(const i32x4*)bp;
            *(i32x4*)&Bs[br * GLS + sc + 8] = *(const i32x4*)(bp + 8);
        }
        __syncthreads();

        #pragma unroll
        for (int ks = 0; ks < 2; ++ks) {
            bf16x8_t af[2], bfr[4];
            #pragma unroll
            for (int mt = 0; mt < 2; ++mt)
                af[mt] = *(const bf16x8_t*)&As[(mt * 16 + lr) * GLS + ks * 32 + lq * 8];
            #pragma unroll
            for (int nt = 0; nt < 4; ++nt)
                bfr[nt] = *(const bf16x8_t*)&Bs[(wn + nt * 16 + lr) * GLS + ks * 32 + lq * 8];
            #pragma unroll
            for (int mt = 0; mt < 2; ++mt)
                #pragma unroll
                for (int nt = 0; nt < 4; ++nt)
                    acc[mt][nt] = __builtin_amdgcn_mfma_f32_16x16x32_bf16(
                        af[mt], bfr[nt], acc[mt][nt], 0, 0, 0);
        }
        __syncthreads();
    }

    float bv[4];
    #pragma unroll
    for (int nt = 0; nt < 4; ++nt)
        bv[nt] = bias[wn + nt * 16 + lr];

    // val = C + b2 + residual; per-row partial sums over this wave's 64 cols
    const unsigned short* hbp = (const unsigned short*)hb;
    #pragma unroll
    for (int mt = 0; mt < 2; ++mt) {
        #pragma unroll
        for (int r = 0; r < 4; ++r) {
            const int rb = mt * 16 + lq * 4 + r;      // 0..31
            const int grow = row0 + rb;               // always < M (625*32 = M)
            float s1 = 0.f, s2 = 0.f;
            #pragma unroll
            for (int nt = 0; nt < 4; ++nt) {
                float res = bf2f(hbp[(size_t)grow * C_DIM + wn + nt * 16 + lr]);
                float v = acc[mt][nt][r] + bv[nt] + res;
                acc[mt][nt][r] = v;                   // keep for normalize phase
                s1 += v; s2 += v * v;
            }
            #pragma unroll
            for (int off = 1; off < 16; off <<= 1) {
                s1 += __shfl_xor(s1, off);
                s2 += __shfl_xor(s2, off);
            }
            if (lr == 0) {
                rsum[0][rb][wave] = s1;
                rsum[1][rb][wave] = s2;
            }
        }
    }
    __syncthreads();

    float g[4], bb[4];
    #pragma unroll
    for (int nt = 0; nt < 4; ++nt) {
        g[nt]  = ln_g[wn + nt * 16 + lr];
        bb[nt] = ln_b[wn + nt * 16 + lr];
    }

    #pragma unroll
    for (int mt = 0; mt < 2; ++mt) {
        #pragma unroll
        for (int r = 0; r < 4; ++r) {
            const int rb = mt * 16 + lq * 4 + r;
            const int grow = row0 + rb;
            float s1 = (rsum[0][rb][0] + rsum[0][rb][1]) + (rsum[0][rb][2] + rsum[0][rb][3]);
            float s2 = (rsum[1][rb][0] + rsum[1][rb][1]) + (rsum[1][rb][2] + rsum[1][rb][3]);
            float mean = s1 * (1.0f / C_DIM);
            float inv = rsqrtf(s2 * (1.0f / C_DIM) - mean * mean + LN_EPS);
            if (out_split) {
                #pragma unroll
                for (int nt = 0; nt < 4; ++nt) {
                    float o = (acc[mt][nt][r] - mean) * inv * g[nt] + bb[nt];
                    int c = wn + nt * 16 + lr;
                    size_t off_ = (c < HID) ? ((size_t)grow * HID + c)
                                            : ((size_t)M * HID + (size_t)grow * HID + (c - HID));
                    out_split[off_] = o;
                }
            } else {
                #pragma unroll
                for (int nt = 0; nt < 4; ++nt) {
                    float o = (acc[mt][nt][r] - mean) * inv * g[nt] + bb[nt];
                    ((unsigned short*)hb)[(size_t)grow * C_DIM + wn + nt * 16 + lr] =
                        __bfloat16_as_ushort(__float2bfloat16(o));
                }
            }
        }
    }
}

// ---------------------------------------------------------------------------
// Fused GAT: per-edge exp weights in-loop + weighted bf16 gather + bias +
// residual (bf16 hb) + LN1. One WAVE per node; lane owns 8 channels (16B
// gathers); two 32-lane halves process disjoint edge halves; combined via
// shfl_xor(32). hb updated in place (bf16-only residual stream).
// ---------------------------------------------------------------------------
__global__ __launch_bounds__(256) void agg_kernel(
    const __hip_bfloat16* __restrict__ xhb, const float* __restrict__ a_s,
    const float* __restrict__ a_d, const int* __restrict__ csr,
    const int* __restrict__ offs, const float* __restrict__ gat_b,
    const float* __restrict__ ln_g, const float* __restrict__ ln_b,
    __hip_bfloat16* __restrict__ hb, int Nn)
{
    const int lane = threadIdx.x & 63;
    const int n = __builtin_amdgcn_readfirstlane(blockIdx.x * 4 + (threadIdx.x >> 6));
    if (n >= Nn) return;
    const int half = lane >> 5;
    const int sl = lane & 31;
    const int head = sl >> 3;            // 8 lanes per head
    const int c0 = sl * 8;               // 8 channels per lane
    const unsigned* x = (const unsigned*)xhb;   // packed bf16 pairs
    const size_t rowp = (size_t)n * (C_DIM / 2) + (c0 >> 1);

    const float ad = a_d[n * 4 + head];

    const int beg = offs[n], end = offs[n + 1];
    const int ne = end - beg;
    const int nh0 = (ne + 1) >> 1;
    int ih  = half ? (beg + nh0) : beg;
    int cnt = half ? (ne - nh0) : nh0;

    // residual from bf16 hb (issue early)
    i32x4 rv = *(const i32x4*)&((const unsigned*)hb)[rowp];

    float acc[8] = {};
    float z = 0.f;

    {
        float wself = __expf(leaky(a_s[n * 4 + head] + ad));
        if (half) {
            i32x4 xv = *(const i32x4*)&x[rowp];
            #pragma unroll
            for (int q = 0; q < 4; ++q) {
                float lo, hi; bf2x((unsigned)xv[q], lo, hi);
                acc[2 * q]     = wself * lo;
                acc[2 * q + 1] = wself * hi;
            }
            z = wself;
        }
    }

    for (; cnt >= 4; cnt -= 4, ih += 4) {
        int s0 = csr[ih], s1 = csr[ih + 1], s2 = csr[ih + 2], s3 = csr[ih + 3];
        float w0 = __expf(leaky(a_s[s0 * 4 + head] + ad));
        float w1 = __expf(leaky(a_s[s1 * 4 + head] + ad));
        float w2 = __expf(leaky(a_s[s2 * 4 + head] + ad));
        float w3 = __expf(leaky(a_s[s3 * 4 + head] + ad));
        i32x4 x0 = *(const i32x4*)&x[(size_t)s0 * (C_DIM / 2) + (c0 >> 1)];
        i32x4 x1 = *(const i32x4*)&x[(size_t)s1 * (C_DIM / 2) + (c0 >> 1)];
        i32x4 x2 = *(const i32x4*)&x[(size_t)s2 * (C_DIM / 2) + (c0 >> 1)];
        i32x4 x3 = *(const i32x4*)&x[(size_t)s3 * (C_DIM / 2) + (c0 >> 1)];
        #pragma unroll
        for (int q = 0; q < 4; ++q) {
            float lo, hi;
            bf2x((unsigned)x0[q], lo, hi);
            acc[2 * q] += w0 * lo; acc[2 * q + 1] += w0 * hi;
            bf2x((unsigned)x1[q], lo, hi);
            acc[2 * q] += w1 * lo; acc[2 * q + 1] += w1 * hi;
            bf2x((unsigned)x2[q], lo, hi);
            acc[2 * q] += w2 * lo; acc[2 * q + 1] += w2 * hi;
            bf2x((unsigned)x3[q], lo, hi);
            acc[2 * q] += w3 * lo; acc[2 * q + 1] += w3 * hi;
        }
        z += (w0 + w1) + (w2 + w3);
    }
    for (; cnt > 0; --cnt, ++ih) {
        int s0 = csr[ih];
        float w0 = __expf(leaky(a_s[s0 * 4 + head] + ad));
        i32x4 x0 = *(const i32x4*)&x[(size_t)s0 * (C_DIM / 2) + (c0 >> 1)];
        #pragma unroll
        for (int q = 0; q < 4; ++q) {
            float lo, hi; bf2x((unsigned)x0[q], lo, hi);
            acc[2 * q] += w0 * lo; acc[2 * q + 1] += w0 * hi;
        }
        z += w0;
    }

    #pragma unroll
    for (int j = 0; j < 8; ++j) acc[j] += __shfl_xor(acc[j], 32);
    z += __shfl_xor(z, 32);

    float res[8];
    #pragma unroll
    for (int q = 0; q < 4; ++q) bf2x((unsigned)rv[q], res[2 * q], res[2 * q + 1]);

    float4 gb0 = *(const float4*)&gat_b[c0];
    float4 gb1 = *(const float4*)&gat_b[c0 + 4];
    float gb[8] = {gb0.x, gb0.y, gb0.z, gb0.w, gb1.x, gb1.y, gb1.z, gb1.w};
    float rz = 1.0f / z;
    float val[8];
    #pragma unroll
    for (int j = 0; j < 8; ++j) val[j] = acc[j] * rz + gb[j] + res[j];

    // LN: each channel appears on 2 lanes -> normalize by 512.
    float s1 = 0.f, s2 = 0.f;
    #pragma unroll
    for (int j = 0; j < 8; ++j) { s1 += val[j]; s2 += val[j] * val[j]; }
    #pragma unroll
    for (int off = 1; off < 64; off <<= 1) {
        s1 += __shfl_xor(s1, off);
        s2 += __shfl_xor(s2, off);
    }
    float mean = s1 * (1.0f / (2 * C_DIM));
    float inv = rsqrtf(s2 * (1.0f / (2 * C_DIM)) - mean * mean + LN_EPS);

    if (half == 0) {
        float4 g0 = *(const float4*)&ln_g[c0];
        float4 g1 = *(const float4*)&ln_g[c0 + 4];
        float4 bb0 = *(const float4*)&ln_b[c0];
        float4 bb1 = *(const float4*)&ln_b[c0 + 4];
        float g[8] = {g0.x, g0.y, g0.z, g0.w, g1.x, g1.y, g1.z, g1.w};
        float bb[8] = {bb0.x, bb0.y, bb0.z, bb0.w, bb1.x, bb1.y, bb1.z, bb1.w};
        float o[8];
        #pragma unroll
        for (int j = 0; j < 8; ++j) o[j] = (val[j] - mean) * inv * g[j] + bb[j];
        i32x4 ob;
        ob[0] = (int)packbf(o[0], o[1]);
        ob[1] = (int)packbf(o[2], o[3]);
        ob[2] = (int)packbf(o[4], o[5]);
        ob[3] = (int)packbf(o[6], o[7]);
        *(i32x4*)&((unsigned*)hb)[rowp] = ob;
    }
}

// ---------------------------------------------------------------------------
// Host launch
// ---------------------------------------------------------------------------
extern "C" void kernel_launch(void* const* d_in, const int* in_sizes, int n_in,
                              void* d_out, int out_size, void* d_ws, size_t ws_size,
                              hipStream_t stream)
{
    const float* hf       = (const float*)d_in[0];
    const float* hs       = (const float*)d_in[1];
    const int*   edge     = (const int*)  d_in[2];
    const float* W        = (const float*)d_in[3];
    const float* att_src  = (const float*)d_in[4];
    const float* att_dst  = (const float*)d_in[5];
    const float* gat_b    = (const float*)d_in[6];
    const float* w1       = (const float*)d_in[7];
    const float* b1       = (const float*)d_in[8];
    const float* w2       = (const float*)d_in[9];
    const float* b2       = (const float*)d_in[10];
    const float* ln1g     = (const float*)d_in[11];
    const float* ln1b     = (const float*)d_in[12];
    const float* ln2g     = (const float*)d_in[13];
    const float* ln2b     = (const float*)d_in[14];
    float* out = (float*)d_out;

    const int N = in_sizes[0] / HID;       // 20000
    const int E = in_sizes[2] / 2;         // 320000
    const int* e_src = edge;
    const int* e_dst = edge + E;

    char* p = (char*)d_ws;
    auto alloc = [&](size_t bytes) {
        char* r = p;
        p += (bytes + 255) & ~(size_t)255;
        return (void*)r;
    };
    const int NPAD = N + 64;               // pad: unguarded GEMM staging/writes past M
    const int NB   = (N + 1023) / 1024;    // scan phase-1 blocks (20)
    __hip_bfloat16* hb     = (__hip_bfloat16*)alloc((size_t)NPAD * C_DIM * 2);
    __hip_bfloat16* xhb    = (__hip_bfloat16*)alloc((size_t)NPAD * C_DIM * 2);  // gemm1 out
    __hip_bfloat16* midb   = (__hip_bfloat16*)alloc((size_t)NPAD * FF_DIM * 2);
    float*          a_s    = (float*)alloc((size_t)NPAD * HEADS * 4);
    float*          a_d    = (float*)alloc((size_t)NPAD * HEADS * 4);
    int*            counts = (int*)alloc((size_t)N * 4);
    int*            offs   = (int*)alloc((size_t)(N + 1) * 4);
    int*            cursor = (int*)alloc((size_t)N * 4);
    int*            csr    = (int*)alloc((size_t)E * 4);
    int*            bsum   = (int*)alloc((size_t)NB * 4);
    __hip_bfloat16* WT     = (__hip_bfloat16*)alloc((size_t)NLAYERS * C_DIM * C_DIM * 2);
    __hip_bfloat16* w1T    = (__hip_bfloat16*)alloc((size_t)NLAYERS * C_DIM * FF_DIM * 2);
    __hip_bfloat16* w2T    = (__hip_bfloat16*)alloc((size_t)NLAYERS * FF_DIM * C_DIM * 2);

    {
        int total = N * (C_DIM / 4);
        concat_kernel<<<(total + 255) / 256, 256, 0, stream>>>(hf, hs, hb, N);
    }
    transp_bf16_kernel<<<dim3(C_DIM / 32, C_DIM / 32, NLAYERS), 256, 0, stream>>>(W, WT, C_DIM, C_DIM);
    transp_bf16_kernel<<<dim3(FF_DIM / 32, C_DIM / 32, NLAYERS), 256, 0, stream>>>(w1, w1T, C_DIM, FF_DIM);
    transp_bf16_kernel<<<dim3(C_DIM / 32, FF_DIM / 32, NLAYERS), 256, 0, stream>>>(w2, w2T, FF_DIM, C_DIM);

    hipMemsetAsync(counts, 0, (size_t)N * 4, stream);
    hist_kernel<<<(E + 255) / 256, 256, 0, stream>>>(e_dst, counts, E);
    scan1_kernel<<<NB, 1024, 0, stream>>>(counts, offs, bsum, N);
    scan2_kernel<<<1, 64, 0, stream>>>(bsum, offs, NB, N);
    scan3_kernel<<<(N + 255) / 256, 256, 0, stream>>>(offs, cursor, bsum, N);
    fill_kernel<<<(E + 255) / 256, 256, 0, stream>>>(e_src, e_dst, cursor, csr, E);

    const int gm = (N + GBM - 1) / GBM;   // 313
    const int gf = (N + FBM - 1) / FBM;   // 625

    for (int l = 0; l < NLAYERS; ++l) {
        const __hip_bfloat16* Wl  = WT  + (size_t)l * C_DIM * C_DIM;
        const __hip_bfloat16* w1l = w1T + (size_t)l * C_DIM * FF_DIM;
        const __hip_bfloat16* w2l = w2T + (size_t)l * FF_DIM * C_DIM;
        const float* asl  = att_src + (size_t)l * C_DIM;
        const float* adl  = att_dst + (size_t)l * C_DIM;
        const float* gbl  = gat_b + (size_t)l * C_DIM;
        const float* b1l  = b1 + (size_t)l * FF_DIM;
        const float* b2l  = b2 + (size_t)l * C_DIM;
        const float* g1l  = ln1g + (size_t)l * C_DIM;
        const float* be1l = ln1b + (size_t)l * C_DIM;
        const float* g2l  = ln2g + (size_t)l * C_DIM;
        const float* be2l = ln2b + (size_t)l * C_DIM;

        // xhb = hb @ W[l] (bf16 out) + fused a_s/a_d epilogue
        gemm_bf16_kernel<<<dim3(gm, C_DIM / GBN), 256, 0, stream>>>(
            hb, Wl, nullptr, xhb, asl, adl, a_s, a_d, N, C_DIM, C_DIM, 0);
        // fused exp-weights + softmax-agg + bias + residual + LN1 (hb in place)
        agg_kernel<<<(N + 3) / 4, 256, 0, stream>>>(
            xhb, a_s, a_d, csr, offs, gbl, g1l, be1l, hb, N);
        // mid = relu(hb @ w1 + b1)  (bf16 out)
        gemm_bf16_kernel<<<dim3(gm, FF_DIM / GBN), 256, 0, stream>>>(
            hb, w1l, b1l, midb, nullptr, nullptr, nullptr, nullptr,
            N, FF_DIM, C_DIM, 1);
        // hb = LN(mid @ w2 + b2 + hb)  [fused gemm3+ln2; final layer -> out]
        gemm3_ln_kernel<<<gf, 256, 0, stream>>>(
            midb, w2l, b2l, g2l, be2l, hb,
            (l == NLAYERS - 1) ? out : nullptr, N);
    }
}